// Round 6
// baseline (447.585 us; speedup 1.0000x reference)
//
#include <hip/hip_runtime.h>

// SGA_75531294867605 — GRU x2 -> cos-sim topK concept graph -> softmax attention head.
// R6: GRU software-pipelined across layers: L1(t) and L0(t+1) are independent
//     given h0(t), so one barrier+phase per step runs both (R5: 2 barriers/step,
//     latency-exposed at 4800cyc/step, VALU 54% / MFMA 27%). Gate math trimmed
//     (merged r/z biases, fma-form blend). sh_x double-buffered.

typedef float f32x4 __attribute__((ext_vector_type(4)));
typedef short s16x8 __attribute__((ext_vector_type(8)));
typedef unsigned short u16;
typedef unsigned long long u64;

#define DEVFN static __device__ __forceinline__

DEVFN u16 f2bf(float f) {
  union { float f; unsigned u; } v; v.f = f;
  return (u16)((v.u + 0x7FFFu + ((v.u >> 16) & 1u)) >> 16);  // RNE
}

DEVFN f32x4 mfma16(s16x8 a, s16x8 b, f32x4 c) {
  return __builtin_amdgcn_mfma_f32_16x16x32_bf16(a, b, c, 0, 0, 0);
}

DEVFN float sigmf(float x) { return __builtin_amdgcn_rcpf(1.f + __expf(-x)); }
DEVFN float tanhf_fast(float x) {
  float e = __expf(2.f * x);
  return 1.f - 2.f * __builtin_amdgcn_rcpf(e + 1.f);
}
DEVFN float lrelu(float v) { return v > 0.f ? v : 0.2f * v; }

// ---------------------------------------------------------------- all-weights fp32->bf16
__global__ void cvt_all(const float* __restrict__ w0, const float* __restrict__ w1,
                        const float* __restrict__ w2, const float* __restrict__ w3,
                        const float* __restrict__ w4, const float* __restrict__ w5,
                        const float* __restrict__ w6, const float* __restrict__ w7,
                        u16* __restrict__ dst) {
  int i = blockIdx.x * 256 + threadIdx.x;
  if (i >= 225280) return;
  float v;
  if      (i < 12288)  v = w0[i];
  else if (i < 61440)  v = w1[i - 12288];
  else if (i < 110592) v = w2[i - 61440];
  else if (i < 159744) v = w3[i - 110592];
  else if (i < 176128) v = w4[i - 159744];
  else if (i < 192512) v = w5[i - 176128];
  else if (i < 208896) v = w6[i - 192512];
  else                 v = w7[i - 208896];
  dst[i] = f2bf(v);
}

// ---------------------------------------------------------------- fused 2-layer GRU
// 512 thr x 16 rows x 64 steps. ONE phase/barrier per step computes L1(t) and
// L0(t+1) concurrently (independent given h0(t)) — cross-layer ILP hides the
// exp-chain and LDS latencies. Weights persist in reg B-frags. All h state dbuf
// in LDS bf16 (bit-identical to R5).
__launch_bounds__(512, 2)
__global__ void gru_fused(const float* __restrict__ x,
                          const u16* __restrict__ Wih0, const u16* __restrict__ Whh0,
                          const float* __restrict__ bih0, const float* __restrict__ bhh0,
                          const u16* __restrict__ Wih1, const u16* __restrict__ Whh1,
                          const float* __restrict__ bih1, const float* __restrict__ bhh1,
                          float* __restrict__ g_out)
{
  const int tid  = threadIdx.x;
  const int w    = tid >> 6;
  const int l    = tid & 63;
  const int quad = l >> 4;
  const int l16  = l & 15;
  const int r0   = blockIdx.x * 16;
  const int c    = w * 16 + l16;

  __shared__ u16 sh_x[2][16 * 40];
  __shared__ u16 sh_h0[2][16 * 136];
  __shared__ u16 sh_h1[2][16 * 136];

  s16x8 B0ih[3];
  s16x8 B0hh[3][4];
  s16x8 B1ih[3][4];
  s16x8 B1hh[3][4];
  float brz0[2], bin0, bhn0, brz1[2], bin1, bhn1;
  {
    int j0g = c, j1g = 128 + c, j2g = 256 + c;
    brz0[0] = bih0[j0g] + bhh0[j0g];  brz0[1] = bih0[j1g] + bhh0[j1g];
    bin0 = bih0[j2g];  bhn0 = bhh0[j2g];
    brz1[0] = bih1[j0g] + bhh1[j0g];  brz1[1] = bih1[j1g] + bhh1[j1g];
    bin1 = bih1[j2g];  bhn1 = bhh1[j2g];
  }
#pragma unroll
  for (int g = 0; g < 3; ++g) {
    int j = g * 128 + c;
    B0ih[g] = *(const s16x8*)(Wih0 + j * 32 + quad * 8);
#pragma unroll
    for (int kk = 0; kk < 4; ++kk) {
      B0hh[g][kk] = *(const s16x8*)(Whh0 + j * 128 + kk * 32 + quad * 8);
      B1ih[g][kk] = *(const s16x8*)(Wih1 + j * 128 + kk * 32 + quad * 8);
      B1hh[g][kk] = *(const s16x8*)(Whh1 + j * 128 + kk * 32 + quad * 8);
    }
  }
  float h0reg[4] = {0.f, 0.f, 0.f, 0.f};
  float h1reg[4] = {0.f, 0.f, 0.f, 0.f};
  for (int idx = tid; idx < 16 * 136; idx += 512) sh_h1[0][idx] = 0;

  const int xr = tid >> 5, xc = tid & 31;
  const float* xrow = x + (size_t)(r0 + xr) * 2048 + xc;
  float xpre = xrow[0];                  // x(0)
  sh_x[0][xr * 40 + xc] = f2bf(xpre);
  xpre = xrow[32];                       // x(1)
  __syncthreads();

  const f32x4 zz4 = {0.f, 0.f, 0.f, 0.f};
  // ---- prologue: h0(0) from x(0), h0(-1)=0
  {
    s16x8 ax = *(const s16x8*)(sh_x[0] + l16 * 40 + quad * 8);
    f32x4 ai[3];
#pragma unroll
    for (int g = 0; g < 3; ++g) ai[g] = mfma16(ax, B0ih[g], zz4);
#pragma unroll
    for (int i = 0; i < 4; ++i) {
      int m = quad * 4 + i;
      float rr = sigmf(ai[0][i] + brz0[0]);
      float zg = sigmf(ai[1][i] + brz0[1]);
      float nn = tanhf_fast(ai[2][i] + bin0 + rr * bhn0);
      float hnew = nn - zg * nn;
      h0reg[i] = hnew;
      sh_h0[0][m * 136 + c] = f2bf(hnew);
    }
  }

  // ---- main: phase t computes L1(t) + L0(t+1), t = 0..62
  for (int t = 0; t < 63; ++t) {
    const int cur = t & 1, nxt = cur ^ 1;
    sh_x[nxt][xr * 40 + xc] = f2bf(xpre);
    __syncthreads();   // h0(t)@cur, h1(t-1)@cur, x(t+1)@nxt visible

    s16x8 ah0[4], ah1[4];
#pragma unroll
    for (int kk = 0; kk < 4; ++kk) {
      ah0[kk] = *(const s16x8*)(sh_h0[cur] + l16 * 136 + kk * 32 + quad * 8);
      ah1[kk] = *(const s16x8*)(sh_h1[cur] + l16 * 136 + kk * 32 + quad * 8);
    }
    s16x8 ax = *(const s16x8*)(sh_x[nxt] + l16 * 40 + quad * 8);
    if (t <= 61) xpre = xrow[(t + 2) * 32];

    // MFMAs for both layers — two independent chains, scheduler interleaves
    f32x4 i1[3], a1[3], i0[3], a0[3];
#pragma unroll
    for (int g = 0; g < 3; ++g) { i1[g] = zz4; a1[g] = zz4; a0[g] = zz4; }
#pragma unroll
    for (int g = 0; g < 3; ++g) i0[g] = mfma16(ax, B0ih[g], zz4);
#pragma unroll
    for (int g = 0; g < 3; ++g)
#pragma unroll
      for (int kk = 0; kk < 4; ++kk) {
        i1[g] = mfma16(ah0[kk], B1ih[g][kk], i1[g]);
        a1[g] = mfma16(ah1[kk], B1hh[g][kk], a1[g]);
        a0[g] = mfma16(ah0[kk], B0hh[g][kk], a0[g]);
      }

    // gates L1(t)
#pragma unroll
    for (int i = 0; i < 4; ++i) {
      int m = quad * 4 + i;
      float rr = sigmf(i1[0][i] + a1[0][i] + brz1[0]);
      float zg = sigmf(i1[1][i] + a1[1][i] + brz1[1]);
      float nn = tanhf_fast(i1[2][i] + bin1 + rr * (a1[2][i] + bhn1));
      float hnew = nn + zg * (h1reg[i] - nn);
      h1reg[i] = hnew;
      sh_h1[nxt][m * 136 + c] = f2bf(hnew);
    }
    // gates L0(t+1)
#pragma unroll
    for (int i = 0; i < 4; ++i) {
      int m = quad * 4 + i;
      float rr = sigmf(i0[0][i] + a0[0][i] + brz0[0]);
      float zg = sigmf(i0[1][i] + a0[1][i] + brz0[1]);
      float nn = tanhf_fast(i0[2][i] + bin0 + rr * (a0[2][i] + bhn0));
      float hnew = nn + zg * (h0reg[i] - nn);
      h0reg[i] = hnew;
      sh_h0[nxt][m * 136 + c] = f2bf(hnew);
    }
  }

  // ---- epilogue: L1(63); h0(63)@buf1, h1(62)@buf1
  __syncthreads();
  {
    s16x8 ah0[4], ah1[4];
#pragma unroll
    for (int kk = 0; kk < 4; ++kk) {
      ah0[kk] = *(const s16x8*)(sh_h0[1] + l16 * 136 + kk * 32 + quad * 8);
      ah1[kk] = *(const s16x8*)(sh_h1[1] + l16 * 136 + kk * 32 + quad * 8);
    }
    f32x4 i1[3], a1[3];
#pragma unroll
    for (int g = 0; g < 3; ++g) { i1[g] = zz4; a1[g] = zz4; }
#pragma unroll
    for (int g = 0; g < 3; ++g)
#pragma unroll
      for (int kk = 0; kk < 4; ++kk) {
        i1[g] = mfma16(ah0[kk], B1ih[g][kk], i1[g]);
        a1[g] = mfma16(ah1[kk], B1hh[g][kk], a1[g]);
      }
#pragma unroll
    for (int i = 0; i < 4; ++i) {
      int m = quad * 4 + i;
      float rr = sigmf(i1[0][i] + a1[0][i] + brz1[0]);
      float zg = sigmf(i1[1][i] + a1[1][i] + brz1[1]);
      float nn = tanhf_fast(i1[2][i] + bin1 + rr * (a1[2][i] + bhn1));
      float hnew = nn + zg * (h1reg[i] - nn);
      g_out[(size_t)(r0 + m) * 128 + c] = hnew;
    }
  }
}

// ---------------------------------------------------------------- row norms + bf16
__global__ void norm_cvt(const float* __restrict__ src, u16* __restrict__ dst,
                         float* __restrict__ rn)
{
  const int tid = threadIdx.x;
  const int wv = tid >> 6, l = tid & 63;
  const int row = blockIdx.x * 4 + wv;
  float2 f2 = *(const float2*)(src + (size_t)row * 128 + l * 2);
  float s = f2.x * f2.x + f2.y * f2.y;
#pragma unroll
  for (int off = 32; off >= 1; off >>= 1) s += __shfl_xor(s, off);
  ushort2 p; p.x = f2bf(f2.x); p.y = f2bf(f2.y);
  *(ushort2*)(dst + (size_t)row * 128 + l * 2) = p;
  if (l == 0) rn[row] = (s == 0.f) ? 0.f : rsqrtf(s);
}

// ---------------------------------------------------------------- cos-sim GEMM
template<int MODE>
__launch_bounds__(256, 1)
__global__ void cos_gemm(const u16* __restrict__ A, const u16* __restrict__ B,
                         const float* __restrict__ rnA, const float* __restrict__ rnB,
                         float* __restrict__ C, u16* __restrict__ E,
                         float* __restrict__ colsum)
{
  __shared__ u16 shA[128 * 136];
  __shared__ u16 shB[128 * 136];
  const int tid = threadIdx.x;
  const int l = tid & 63, wv = tid >> 6;
  const int quad = l >> 4, l16 = l & 15;
  const int i0 = blockIdx.y * 128, j0 = blockIdx.x * 128;
  {
    int r = tid >> 1, half = tid & 1;
    const int4* sa = (const int4*)(A + (size_t)(i0 + r) * 128 + half * 64);
    int4* da = (int4*)(shA + r * 136 + half * 64);
    const int4* sb = (const int4*)(B + (size_t)(j0 + r) * 128 + half * 64);
    int4* db = (int4*)(shB + r * 136 + half * 64);
#pragma unroll
    for (int q = 0; q < 8; ++q) { da[q] = sa[q]; db[q] = sb[q]; }
  }
  __syncthreads();
  const int wm = wv >> 1, wn = wv & 1;
  f32x4 acc[4][4];
  const f32x4 zz4 = {0.f, 0.f, 0.f, 0.f};
#pragma unroll
  for (int a = 0; a < 4; ++a)
#pragma unroll
    for (int b = 0; b < 4; ++b) acc[a][b] = zz4;
#pragma unroll
  for (int kk = 0; kk < 4; ++kk) {
    s16x8 af[4], bfr[4];
#pragma unroll
    for (int mt = 0; mt < 4; ++mt)
      af[mt] = *(const s16x8*)(shA + (wm * 64 + mt * 16 + l16) * 136 + kk * 32 + quad * 8);
#pragma unroll
    for (int nt = 0; nt < 4; ++nt)
      bfr[nt] = *(const s16x8*)(shB + (wn * 64 + nt * 16 + l16) * 136 + kk * 32 + quad * 8);
#pragma unroll
    for (int mt = 0; mt < 4; ++mt)
#pragma unroll
      for (int nt = 0; nt < 4; ++nt) acc[mt][nt] = mfma16(af[mt], bfr[nt], acc[mt][nt]);
  }
  float ra[4][4];
#pragma unroll
  for (int mt = 0; mt < 4; ++mt)
#pragma unroll
    for (int i = 0; i < 4; ++i) ra[mt][i] = rnA[i0 + wm * 64 + mt * 16 + quad * 4 + i];
#pragma unroll
  for (int nt = 0; nt < 4; ++nt) {
    int col = j0 + wn * 64 + nt * 16 + l16;
    float rb = rnB[col];
    float psum = 0.f;
#pragma unroll
    for (int mt = 0; mt < 4; ++mt)
#pragma unroll
      for (int i = 0; i < 4; ++i) {
        int row = i0 + wm * 64 + mt * 16 + quad * 4 + i;
        float v = acc[mt][nt][i] * ra[mt][i] * rb;
        if constexpr (MODE == 0) {
          C[(size_t)row * 4096 + col] = v;
        } else {
          float e = __expf(v);
          E[(size_t)row * 4096 + col] = f2bf(e);
          psum += e;
        }
      }
    if constexpr (MODE == 1) {
      psum += __shfl_xor(psum, 16);
      psum += __shfl_xor(psum, 32);
      if (quad == 0) atomicAdd(colsum + col, psum);
    }
  }
}

// ---------------------------------------------------------------- topK select (no scatter)
__launch_bounds__(256, 1)
__global__ void topk_select(const float* __restrict__ sim,
                            int* __restrict__ gselj, float* __restrict__ gselv,
                            int* __restrict__ cnt, int* __restrict__ touched)
{
  __shared__ unsigned hist[2048];
  __shared__ u64 cand[3072];
  __shared__ int selj[20];
  __shared__ unsigned ws4[4];
  __shared__ int shb, shcnt;
  const int tid = threadIdx.x;
  const int row = blockIdx.x;
  const int l = tid & 63, wv = tid >> 6;

  for (int i = tid; i < 2048; i += 256) hist[i] = 0;
  if (tid == 0) shcnt = 0;
  __syncthreads();

  unsigned key[4][4];
#pragma unroll
  for (int q = 0; q < 4; ++q) {
    int e0 = (q * 256 + tid) * 4;
    float4 v = *(const float4*)(sim + (size_t)row * 4096 + e0);
    key[q][0] = (e0 + 0 == row) ? 0u : (__float_as_uint(v.x) & 0x7FFFFFFFu);
    key[q][1] = (e0 + 1 == row) ? 0u : (__float_as_uint(v.y) & 0x7FFFFFFFu);
    key[q][2] = (e0 + 2 == row) ? 0u : (__float_as_uint(v.z) & 0x7FFFFFFFu);
    key[q][3] = (e0 + 3 == row) ? 0u : (__float_as_uint(v.w) & 0x7FFFFFFFu);
#pragma unroll
    for (int c = 0; c < 4; ++c) {
      unsigned bin = key[q][c] >> 19; if (bin > 2047u) bin = 2047u;
      atomicAdd(&hist[bin], 1u);
    }
  }
  __syncthreads();

  unsigned s = 0;
#pragma unroll
  for (int j = 0; j < 8; ++j) s += hist[tid * 8 + j];
  unsigned r = s;
#pragma unroll
  for (int off = 1; off < 64; off <<= 1) {
    unsigned o = __shfl_down(r, off);
    if (l + off < 64) r += o;
  }
  if (l == 0) ws4[wv] = r;
  __syncthreads();
  unsigned upper = 0;
  for (int q = wv + 1; q < 4; ++q) upper += ws4[q];
  unsigned excl = upper + (r - s);
  if (excl < 20u && excl + s >= 20u) {
    unsigned cum = excl;
    for (int j = 7; j >= 0; --j) {
      cum += hist[tid * 8 + j];
      if (cum >= 20u) { shb = tid * 8 + j; break; }
    }
  }
  __syncthreads();
  const unsigned b = (unsigned)shb;

#pragma unroll
  for (int q = 0; q < 4; ++q) {
    int e0 = (q * 256 + tid) * 4;
#pragma unroll
    for (int c = 0; c < 4; ++c) {
      unsigned bin = key[q][c] >> 19; if (bin > 2047u) bin = 2047u;
      if (bin >= b) {
        int p = atomicAdd(&shcnt, 1);
        if (p < 3072) cand[p] = ((u64)key[q][c] << 32) | (u64)(4095 - (e0 + c));
      }
    }
  }
  __syncthreads();
  const int C = (shcnt < 3072) ? shcnt : 3072;

  if (wv == 0) {
    for (int it = 0; it < 20; ++it) {
      u64 best = 0ull; int bpos = -1;
      for (int p = l; p < C; p += 64) {
        u64 cv = cand[p];
        if (cv > best) { best = cv; bpos = p; }
      }
      u64 mine = best;
#pragma unroll
      for (int off = 1; off < 64; off <<= 1) {
        u64 o = __shfl_xor(best, off);
        if (o > best) best = o;
      }
      if (mine == best && bpos >= 0 && best != 0ull) cand[bpos] = 0ull;
      if (l == 0) selj[it] = 4095 - (int)(best & 0xFFFull);
    }
  }
  __syncthreads();
  if (tid < 20) {
    int idx = selj[tid];
    float sv = (idx == row) ? 0.f : sim[(size_t)row * 4096 + idx];
    gselj[row * 20 + tid] = idx;
    gselv[row * 20 + tid] = sv;
    atomicAdd(&cnt[idx], 1);
    if (sv != 0.f) atomicOr(touched + idx, 1);
  }
}

// ---------------------------------------------------------------- exclusive scan of cnt[4096]
__launch_bounds__(1024, 1)
__global__ void scan4096(const int* __restrict__ cnt, int* __restrict__ offs,
                         int* __restrict__ cur)
{
  __shared__ int wsum[16];
  const int t = threadIdx.x, l = t & 63, wv = t >> 6;
  int4 c = ((const int4*)cnt)[t];
  int s = c.x + c.y + c.z + c.w;
  int ps = s;
#pragma unroll
  for (int off = 1; off < 64; off <<= 1) {
    int o = __shfl_up(ps, off);
    if (l >= off) ps += o;
  }
  if (l == 63) wsum[wv] = ps;
  __syncthreads();
  if (t == 0) {
    int a = 0;
#pragma unroll
    for (int q = 0; q < 16; ++q) { int x = wsum[q]; wsum[q] = a; a += x; }
  }
  __syncthreads();
  int base = wsum[wv] + (ps - s);
  int4 o4;
  o4.x = base; o4.y = o4.x + c.x; o4.z = o4.y + c.y; o4.w = o4.z + c.z;
  ((int4*)offs)[t] = o4;
  ((int4*)cur)[t] = o4;
}

// ---------------------------------------------------------------- CSR entry scatter
__global__ void scatter_entries(const int* __restrict__ gselj, const float* __restrict__ gselv,
                                int* __restrict__ cur, int* __restrict__ eid,
                                float* __restrict__ ev)
{
  unsigned idx = blockIdx.x * 256 + threadIdx.x;
  unsigned row = idx / 20u;
  int j = gselj[idx]; float v = gselv[idx];
  int pos = atomicAdd(&cur[j], 1);
  eid[pos] = (int)row; ev[pos] = v;
}

// ---------------------------------------------------------------- concept gather + cf fused
__launch_bounds__(128, 1)
__global__ void concept_cf(const int* __restrict__ offs, const int* __restrict__ cnt,
                           const int* __restrict__ eid, const float* __restrict__ ev,
                           const float* __restrict__ g, const float* __restrict__ sim,
                           const int* __restrict__ touched,
                           const float* __restrict__ Whc, const float* __restrict__ bhc,
                           float* __restrict__ cf, u16* __restrict__ cfbf,
                           float* __restrict__ rncf)
{
  __shared__ float shc[128];
  __shared__ float red2[2];
  const int j = blockIdx.x, d = threadIdx.x;
  const int l = d & 63, wv = d >> 6;
  const int off = offs[j], n = cnt[j];
  float acc = 0.f;
  for (int p = 0; p < n; ++p) {
    int i = eid[off + p]; float v = ev[off + p];
    acc += v * g[(size_t)i * 128 + d];
  }
  if (touched[j]) acc += sim[(size_t)j * 4097] * g[(size_t)j * 128 + d];
  float s = acc;
#pragma unroll
  for (int o = 32; o >= 1; o >>= 1) s += __shfl_xor(s, o);
  if (l == 0) red2[wv] = s;
  shc[d] = acc;
  __syncthreads();
  float valid = ((red2[0] + red2[1]) != 0.f) ? 1.f : 0.f;
  float o = bhc[d];
  const float4* wr = (const float4*)(Whc + (size_t)d * 128);
#pragma unroll 8
  for (int q = 0; q < 32; ++q) {
    float4 w4 = wr[q];
    float4 c4 = *((const float4*)shc + q);
    o += c4.x * w4.x + c4.y * w4.y + c4.z * w4.z + c4.w * w4.w;
  }
  float cfv = lrelu(o) * valid;
  cf[(size_t)j * 128 + d] = cfv;
  cfbf[(size_t)j * 128 + d] = f2bf(cfv);
  __syncthreads();
  float nn = cfv * cfv;
#pragma unroll
  for (int of = 32; of >= 1; of >>= 1) nn += __shfl_xor(nn, of);
  if (l == 0) red2[wv] = nn;
  __syncthreads();
  if (d == 0) {
    float q2 = red2[0] + red2[1];
    rncf[j] = (q2 == 0.f) ? 0.f : rsqrtf(q2);
  }
}

// ---------------------------------------------------------------- cfTs[n][c] = bf16(cf[c][n]/Z[c])
__global__ void scale_cfT(const float* __restrict__ cf, const float* __restrict__ colsum,
                          u16* __restrict__ cfTs)
{
  int idx = blockIdx.x * 256 + threadIdx.x;
  int n = idx >> 12, c = idx & 4095;
  float rz = __builtin_amdgcn_rcpf(colsum[c]);
  cfTs[idx] = f2bf(cf[(size_t)c * 128 + n] * rz);
}

// ---------------------------------------------------------------- hs_pre = E @ cfTs.T
__launch_bounds__(256, 1)
__global__ void attn_cf(const u16* __restrict__ attn, const u16* __restrict__ cfT,
                        float* __restrict__ hs_pre)
{
  __shared__ u16 shw[16 * 136];
  const int tid = threadIdx.x;
  const int l = tid & 63, wv = tid >> 6;
  const int quad = l >> 4, l16 = l & 15;
  const int r0 = blockIdx.x * 16;
  f32x4 acc[2];
  const f32x4 zz4 = {0.f, 0.f, 0.f, 0.f};
  acc[0] = zz4; acc[1] = zz4;
  for (int kc = 0; kc < 32; ++kc) {
    if (kc) __syncthreads();
    {
      int r = tid >> 4, seg = tid & 15;
      *(int4*)(shw + r * 136 + seg * 8) =
        *(const int4*)(attn + (size_t)(r0 + r) * 4096 + kc * 128 + seg * 8);
    }
    __syncthreads();
#pragma unroll
    for (int kk = 0; kk < 4; ++kk) {
      s16x8 a = *(const s16x8*)(shw + l16 * 136 + kk * 32 + quad * 8);
#pragma unroll
      for (int nt = 0; nt < 2; ++nt) {
        int n = wv * 32 + nt * 16 + l16;
        s16x8 b = *(const s16x8*)(cfT + (size_t)n * 4096 + kc * 128 + kk * 32 + quad * 8);
        acc[nt] = mfma16(a, b, acc[nt]);
      }
    }
  }
#pragma unroll
  for (int nt = 0; nt < 2; ++nt)
#pragma unroll
    for (int i = 0; i < 4; ++i) {
      int row = r0 + quad * 4 + i;
      int col = wv * 32 + nt * 16 + l16;
      hs_pre[(size_t)row * 128 + col] = acc[nt][i];
    }
}

// ---------------------------------------------------------------- head: MFMA chain
__launch_bounds__(256, 1)
__global__ void head_kernel(const float* __restrict__ hs_pre, const float* __restrict__ g,
                            const u16* __restrict__ whs, const u16* __restrict__ wfore,
                            const u16* __restrict__ wback, const u16* __restrict__ windi,
                            const float* __restrict__ b_hs, const float* __restrict__ b_fore,
                            const float* __restrict__ b_back, const float* __restrict__ b_indi,
                            const float* __restrict__ W_out, const float* __restrict__ b_out,
                            float* __restrict__ outp)
{
  __shared__ u16 bufin[16 * 136];
  __shared__ u16 bufB[16 * 136];
  __shared__ float bufF[16 * 132];
  __shared__ float shWout[128];
  const int tid = threadIdx.x;
  const int l = tid & 63, wv = tid >> 6;
  const int quad = l >> 4, l16 = l & 15;
  const int r0 = blockIdx.x * 16;
  const f32x4 zz4 = {0.f, 0.f, 0.f, 0.f};

  if (tid < 128) shWout[tid] = W_out[tid];
  for (int idx = tid; idx < 2048; idx += 256) {
    int j = idx >> 7, n = idx & 127;
    bufin[j * 136 + n] = f2bf(hs_pre[(size_t)(r0 + j) * 128 + n]);
  }
  __syncthreads();
  {
    s16x8 a[4];
#pragma unroll
    for (int kk = 0; kk < 4; ++kk)
      a[kk] = *(const s16x8*)(bufin + l16 * 136 + kk * 32 + quad * 8);
    f32x4 acc[2]; acc[0] = zz4; acc[1] = zz4;
#pragma unroll
    for (int nt = 0; nt < 2; ++nt) {
      int n = wv * 32 + nt * 16 + l16;
#pragma unroll
      for (int kk = 0; kk < 4; ++kk)
        acc[nt] = mfma16(a[kk], *(const s16x8*)(whs + n * 128 + kk * 32 + quad * 8), acc[nt]);
    }
#pragma unroll
    for (int nt = 0; nt < 2; ++nt) {
      int n = wv * 32 + nt * 16 + l16;
      float bb = b_hs[n];
#pragma unroll
      for (int i = 0; i < 4; ++i)
        bufB[(quad * 4 + i) * 136 + n] = f2bf(lrelu(acc[nt][i] + bb));
    }
  }
  __syncthreads();
  {
    s16x8 a[4];
#pragma unroll
    for (int kk = 0; kk < 4; ++kk)
      a[kk] = *(const s16x8*)(bufB + l16 * 136 + kk * 32 + quad * 8);
    f32x4 aF[2], aB[2]; aF[0] = zz4; aF[1] = zz4; aB[0] = zz4; aB[1] = zz4;
#pragma unroll
    for (int nt = 0; nt < 2; ++nt) {
      int n = wv * 32 + nt * 16 + l16;
#pragma unroll
      for (int kk = 0; kk < 4; ++kk) {
        aF[nt] = mfma16(a[kk], *(const s16x8*)(wfore + n * 128 + kk * 32 + quad * 8), aF[nt]);
        aB[nt] = mfma16(a[kk], *(const s16x8*)(wback + n * 128 + kk * 32 + quad * 8), aB[nt]);
      }
    }
#pragma unroll
    for (int nt = 0; nt < 2; ++nt) {
      int n = wv * 32 + nt * 16 + l16;
      float bf_ = b_fore[n], bb_ = b_back[n];
#pragma unroll
      for (int i = 0; i < 4; ++i) {
        int m = quad * 4 + i;
        bufF[m * 132 + n] = lrelu(aF[nt][i] + bf_);
        float back = lrelu(aB[nt][i] + bb_);
        float gv = g[(size_t)(r0 + m) * 128 + n];
        bufin[m * 136 + n] = f2bf(gv - back);
      }
    }
  }
  __syncthreads();
  {
    s16x8 a[4];
#pragma unroll
    for (int kk = 0; kk < 4; ++kk)
      a[kk] = *(const s16x8*)(bufin + l16 * 136 + kk * 32 + quad * 8);
    f32x4 acc[2]; acc[0] = zz4; acc[1] = zz4;
#pragma unroll
    for (int nt = 0; nt < 2; ++nt) {
      int n = wv * 32 + nt * 16 + l16;
#pragma unroll
      for (int kk = 0; kk < 4; ++kk)
        acc[nt] = mfma16(a[kk], *(const s16x8*)(windi + n * 128 + kk * 32 + quad * 8), acc[nt]);
    }
#pragma unroll
    for (int nt = 0; nt < 2; ++nt) {
      int n = wv * 32 + nt * 16 + l16;
      float bi_ = b_indi[n];
#pragma unroll
      for (int i = 0; i < 4; ++i)
        bufF[(quad * 4 + i) * 132 + n] += lrelu(acc[nt][i] + bi_);
    }
  }
  __syncthreads();
  if (tid < 16) {
    float s = b_out[0];
    const float* fr = bufF + tid * 132;
    for (int n = 0; n < 128; ++n) s += fr[n] * shWout[n];
    outp[r0 + tid] = s;
  }
}

// ---------------------------------------------------------------- workspace layout
static const size_t OFF_A       = 0;             // 67,108,864  sim fp32
static const size_t OFF_ATTN    = 67108864;      // 33,554,432  attn numerator bf16
static const size_t OFF_G       = 100663296;
static const size_t OFF_GBF     = 102760448;
static const size_t OFF_RNG     = 103809024;
static const size_t OFF_SELJ    = 103825408;
static const size_t OFF_SELV    = 104153088;
static const size_t OFF_EID     = 104480768;
static const size_t OFF_EV      = 104808448;
static const size_t OFF_CNT     = 105136128;
static const size_t OFF_TOUCH   = 105152512;
static const size_t OFF_COLSUM  = 105168896;
static const size_t OFF_OFFS    = 105185280;
static const size_t OFF_CUR     = 105201664;
static const size_t OFF_CF      = 105218048;
static const size_t OFF_CFBF    = 107315200;
static const size_t OFF_CFTS    = 108363776;
static const size_t OFF_RNCF    = 109412352;
static const size_t OFF_HSPRE   = 109428736;
static const size_t OFF_WB      = 111525888;

extern "C" void kernel_launch(void* const* d_in, const int* in_sizes, int n_in,
                              void* d_out, int out_size, void* d_ws, size_t ws_size,
                              hipStream_t stream)
{
  (void)in_sizes; (void)n_in; (void)out_size; (void)ws_size;
  const float* x      = (const float*)d_in[0];
  const float* Wih0   = (const float*)d_in[1];
  const float* Whh0   = (const float*)d_in[2];
  const float* bih0   = (const float*)d_in[3];
  const float* bhh0   = (const float*)d_in[4];
  const float* Wih1   = (const float*)d_in[5];
  const float* Whh1   = (const float*)d_in[6];
  const float* bih1   = (const float*)d_in[7];
  const float* bhh1   = (const float*)d_in[8];
  const float* W_hc   = (const float*)d_in[9];
  const float* b_hc   = (const float*)d_in[10];
  const float* W_hs   = (const float*)d_in[11];
  const float* b_hs   = (const float*)d_in[12];
  const float* W_fore = (const float*)d_in[13];
  const float* b_fore = (const float*)d_in[14];
  const float* W_back = (const float*)d_in[15];
  const float* b_back = (const float*)d_in[16];
  const float* W_indi = (const float*)d_in[17];
  const float* b_indi = (const float*)d_in[18];
  const float* W_out  = (const float*)d_in[19];
  const float* b_out  = (const float*)d_in[20];

  char* ws = (char*)d_ws;
  float* simbuf  = (float*)(ws + OFF_A);
  u16*   attnb   = (u16*)(ws + OFF_ATTN);
  float* gbuf    = (float*)(ws + OFF_G);
  u16*   gbf     = (u16*)(ws + OFF_GBF);
  float* rng     = (float*)(ws + OFF_RNG);
  int*   gselj   = (int*)(ws + OFF_SELJ);
  float* gselv   = (float*)(ws + OFF_SELV);
  int*   eid     = (int*)(ws + OFF_EID);
  float* ev      = (float*)(ws + OFF_EV);
  int*   cntb    = (int*)(ws + OFF_CNT);
  int*   touched = (int*)(ws + OFF_TOUCH);
  float* colsum  = (float*)(ws + OFF_COLSUM);
  int*   offsb   = (int*)(ws + OFF_OFFS);
  int*   curb    = (int*)(ws + OFF_CUR);
  float* cf      = (float*)(ws + OFF_CF);
  u16*   cfbf    = (u16*)(ws + OFF_CFBF);
  u16*   cfTs    = (u16*)(ws + OFF_CFTS);
  float* rncf    = (float*)(ws + OFF_RNCF);
  float* hs_pre  = (float*)(ws + OFF_HSPRE);
  u16*   wsB     = (u16*)(ws + OFF_WB);
  u16 *wih0b = wsB, *whh0b = wsB + 12288, *wih1b = wsB + 61440, *whh1b = wsB + 110592;
  u16 *whsb = wsB + 159744, *wforeb = wsB + 176128, *wbackb = wsB + 192512, *windib = wsB + 208896;

  cvt_all<<<880, 256, 0, stream>>>(Wih0, Whh0, Wih1, Whh1, W_hs, W_fore, W_back, W_indi, wsB);

  gru_fused<<<256, 512, 0, stream>>>(x, wih0b, whh0b, bih0, bhh0,
                                     wih1b, whh1b, bih1, bhh1, gbuf);

  norm_cvt<<<1024, 256, 0, stream>>>(gbuf, gbf, rng);
  cos_gemm<0><<<dim3(32, 32), 256, 0, stream>>>(gbf, gbf, rng, rng, simbuf,
                                                (u16*)nullptr, (float*)nullptr);

  hipMemsetAsync(ws + OFF_CNT, 0, 49152, stream);
  topk_select<<<4096, 256, 0, stream>>>(simbuf, gselj, gselv, cntb, touched);
  scan4096<<<1, 1024, 0, stream>>>(cntb, offsb, curb);
  scatter_entries<<<320, 256, 0, stream>>>(gselj, gselv, curb, eid, ev);
  concept_cf<<<4096, 128, 0, stream>>>(offsb, cntb, eid, ev, gbuf, simbuf, touched,
                                       W_hc, b_hc, cf, cfbf, rncf);

  cos_gemm<1><<<dim3(32, 32), 256, 0, stream>>>(gbf, cfbf, rng, rncf, (float*)nullptr,
                                                attnb, colsum);
  scale_cfT<<<2048, 256, 0, stream>>>(cf, colsum, cfTs);
  attn_cf<<<256, 256, 0, stream>>>(attnb, cfTs, hs_pre);

  head_kernel<<<256, 256, 0, stream>>>(hs_pre, gbuf, whsb, wforeb, wbackb, windib,
                                       b_hs, b_fore, b_back, b_indi, W_out, b_out,
                                       (float*)d_out);
}

// Round 8
// 431.126 us; speedup vs baseline: 1.0382x; 1.0382x over previous
//
#include <hip/hip_runtime.h>
#include <hip/hip_bf16.h>

// SGA_75531294867605 — GRU x2 -> cos-sim topK concept graph -> softmax attention head.
// R8: fix R7's n-gate bug — GRU n = tanh(i_n + b_in + r*(h_n + b_hn)): the reset
//     gate scales ONLY the h-side matmul, so i_n/h_n need separate accumulators.
//     r/z gates stay chained (legal). Packed bf16 cvt kept. 8 live f32x4 accs.

typedef float f32x4 __attribute__((ext_vector_type(4)));
typedef short s16x8 __attribute__((ext_vector_type(8)));
typedef unsigned short u16;
typedef unsigned long long u64;

#define DEVFN static __device__ __forceinline__

DEVFN u16 f2bf(float f) {
  union { float f; unsigned u; } v; v.f = f;
  return (u16)((v.u + 0x7FFFu + ((v.u >> 16) & 1u)) >> 16);  // RNE
}

DEVFN unsigned f2bf_pk(float lo, float hi) {   // low16=bf16(lo), high16=bf16(hi)
  union { __hip_bfloat162 h; unsigned u; } p;
  p.h = __float22bfloat162_rn(make_float2(lo, hi));
  return p.u;
}

DEVFN f32x4 mfma16(s16x8 a, s16x8 b, f32x4 c) {
  return __builtin_amdgcn_mfma_f32_16x16x32_bf16(a, b, c, 0, 0, 0);
}

DEVFN float sigmf(float x) { return __builtin_amdgcn_rcpf(1.f + __expf(-x)); }
DEVFN float tanhf_fast(float x) {
  float e = __expf(2.f * x);
  return 1.f - 2.f * __builtin_amdgcn_rcpf(e + 1.f);
}
DEVFN float lrelu(float v) { return v > 0.f ? v : 0.2f * v; }

// ---------------------------------------------------------------- all-weights fp32->bf16
__global__ void cvt_all(const float* __restrict__ w0, const float* __restrict__ w1,
                        const float* __restrict__ w2, const float* __restrict__ w3,
                        const float* __restrict__ w4, const float* __restrict__ w5,
                        const float* __restrict__ w6, const float* __restrict__ w7,
                        u16* __restrict__ dst) {
  int i = blockIdx.x * 256 + threadIdx.x;
  if (i >= 225280) return;
  float v;
  if      (i < 12288)  v = w0[i];
  else if (i < 61440)  v = w1[i - 12288];
  else if (i < 110592) v = w2[i - 61440];
  else if (i < 159744) v = w3[i - 110592];
  else if (i < 176128) v = w4[i - 159744];
  else if (i < 192512) v = w5[i - 176128];
  else if (i < 208896) v = w6[i - 192512];
  else                 v = w7[i - 208896];
  dst[i] = f2bf(v);
}

// ---------------------------------------------------------------- fused 2-layer GRU
__launch_bounds__(512, 2)
__global__ void gru_fused(const float* __restrict__ x,
                          const u16* __restrict__ Wih0, const u16* __restrict__ Whh0,
                          const float* __restrict__ bih0, const float* __restrict__ bhh0,
                          const u16* __restrict__ Wih1, const u16* __restrict__ Whh1,
                          const float* __restrict__ bih1, const float* __restrict__ bhh1,
                          float* __restrict__ g_out)
{
  const int tid  = threadIdx.x;
  const int w    = tid >> 6;
  const int l    = tid & 63;
  const int quad = l >> 4;
  const int l16  = l & 15;
  const int r0   = blockIdx.x * 16;
  const int c    = w * 16 + l16;

  __shared__ u16 sh_x[2][16 * 40];
  __shared__ u16 sh_h0[2][16 * 136];
  __shared__ u16 sh_h1[2][16 * 136];

  s16x8 B0ih[3];
  s16x8 B0hh[3][4];
  s16x8 B1ih[3][4];
  s16x8 B1hh[3][4];
  float brz0[2], bin0, bhn0, brz1[2], bin1, bhn1;
  {
    int j0g = c, j1g = 128 + c, j2g = 256 + c;
    brz0[0] = bih0[j0g] + bhh0[j0g];  brz0[1] = bih0[j1g] + bhh0[j1g];
    bin0 = bih0[j2g];  bhn0 = bhh0[j2g];
    brz1[0] = bih1[j0g] + bhh1[j0g];  brz1[1] = bih1[j1g] + bhh1[j1g];
    bin1 = bih1[j2g];  bhn1 = bhh1[j2g];
  }
#pragma unroll
  for (int g = 0; g < 3; ++g) {
    int j = g * 128 + c;
    B0ih[g] = *(const s16x8*)(Wih0 + j * 32 + quad * 8);
#pragma unroll
    for (int kk = 0; kk < 4; ++kk) {
      B0hh[g][kk] = *(const s16x8*)(Whh0 + j * 128 + kk * 32 + quad * 8);
      B1ih[g][kk] = *(const s16x8*)(Wih1 + j * 128 + kk * 32 + quad * 8);
      B1hh[g][kk] = *(const s16x8*)(Whh1 + j * 128 + kk * 32 + quad * 8);
    }
  }
  float h0reg[4] = {0.f, 0.f, 0.f, 0.f};
  float h1reg[4] = {0.f, 0.f, 0.f, 0.f};
  for (int idx = tid; idx < 16 * 136; idx += 512) sh_h1[0][idx] = 0;

  const int xr = tid >> 5, xc = tid & 31;
  const float* xrow = x + (size_t)(r0 + xr) * 2048 + xc;
  float xpre = xrow[0];                  // x(0)
  sh_x[0][xr * 40 + xc] = f2bf(xpre);
  xpre = xrow[32];                       // x(1)
  __syncthreads();

  const f32x4 zz4 = {0.f, 0.f, 0.f, 0.f};
  // ---- prologue: h0(0) from x(0), h0(-1)=0 (h-matmuls are 0; bhh still applies)
  {
    s16x8 ax = *(const s16x8*)(sh_x[0] + l16 * 40 + quad * 8);
    f32x4 ai[3];
#pragma unroll
    for (int g = 0; g < 3; ++g) ai[g] = mfma16(ax, B0ih[g], zz4);
#pragma unroll
    for (int i = 0; i < 4; i += 2) {
      float hn[2];
#pragma unroll
      for (int q = 0; q < 2; ++q) {
        int ii = i + q;
        float rr = sigmf(ai[0][ii] + brz0[0]);
        float zg = sigmf(ai[1][ii] + brz0[1]);
        float nn = tanhf_fast(ai[2][ii] + bin0 + rr * bhn0);
        hn[q] = nn - zg * nn;
        h0reg[ii] = hn[q];
      }
      unsigned pk = f2bf_pk(hn[0], hn[1]);
      int m = quad * 4 + i;
      sh_h0[0][m * 136 + c]       = (u16)pk;
      sh_h0[0][(m + 1) * 136 + c] = (u16)(pk >> 16);
    }
  }

  // ---- main: phase t computes L1(t) + L0(t+1), t = 0..62
  for (int t = 0; t < 63; ++t) {
    const int cur = t & 1, nxt = cur ^ 1;
    sh_x[nxt][xr * 40 + xc] = f2bf(xpre);
    __syncthreads();   // h0(t)@cur, h1(t-1)@cur, x(t+1)@nxt visible

    s16x8 ah0[4], ah1[4];
#pragma unroll
    for (int kk = 0; kk < 4; ++kk) {
      ah0[kk] = *(const s16x8*)(sh_h0[cur] + l16 * 136 + kk * 32 + quad * 8);
      ah1[kk] = *(const s16x8*)(sh_h1[cur] + l16 * 136 + kk * 32 + quad * 8);
    }
    s16x8 ax = *(const s16x8*)(sh_x[nxt] + l16 * 40 + quad * 8);
    if (t <= 61) xpre = xrow[(t + 2) * 32];

    // accumulators: r/z chained (i+h legal inside sigmoid); n-gate i/h SEPARATE.
    f32x4 r1a, z1a, ni1, nh1, r0a, z0a, ni0, nh0;
    r1a = mfma16(ah0[0], B1ih[0][0], zz4);
    z1a = mfma16(ah0[0], B1ih[1][0], zz4);
    ni1 = mfma16(ah0[0], B1ih[2][0], zz4);
    nh1 = mfma16(ah1[0], B1hh[2][0], zz4);
    r0a = mfma16(ax, B0ih[0], zz4);
    z0a = mfma16(ax, B0ih[1], zz4);
    ni0 = mfma16(ax, B0ih[2], zz4);
    nh0 = mfma16(ah0[0], B0hh[2][0], zz4);
#pragma unroll
    for (int kk = 1; kk < 4; ++kk) {
      r1a = mfma16(ah0[kk], B1ih[0][kk], r1a);
      z1a = mfma16(ah0[kk], B1ih[1][kk], z1a);
      ni1 = mfma16(ah0[kk], B1ih[2][kk], ni1);
      nh1 = mfma16(ah1[kk], B1hh[2][kk], nh1);
      nh0 = mfma16(ah0[kk], B0hh[2][kk], nh0);
    }
#pragma unroll
    for (int kk = 0; kk < 4; ++kk) {
      r1a = mfma16(ah1[kk], B1hh[0][kk], r1a);
      z1a = mfma16(ah1[kk], B1hh[1][kk], z1a);
      r0a = mfma16(ah0[kk], B0hh[0][kk], r0a);
      z0a = mfma16(ah0[kk], B0hh[1][kk], z0a);
    }

    // gates L1(t)
#pragma unroll
    for (int i = 0; i < 4; i += 2) {
      float hn[2];
#pragma unroll
      for (int q = 0; q < 2; ++q) {
        int ii = i + q;
        float rr = sigmf(r1a[ii] + brz1[0]);
        float zg = sigmf(z1a[ii] + brz1[1]);
        float nn = tanhf_fast(ni1[ii] + bin1 + rr * (nh1[ii] + bhn1));
        hn[q] = nn + zg * (h1reg[ii] - nn);
        h1reg[ii] = hn[q];
      }
      unsigned pk = f2bf_pk(hn[0], hn[1]);
      int m = quad * 4 + i;
      sh_h1[nxt][m * 136 + c]       = (u16)pk;
      sh_h1[nxt][(m + 1) * 136 + c] = (u16)(pk >> 16);
    }
    // gates L0(t+1)
#pragma unroll
    for (int i = 0; i < 4; i += 2) {
      float hn[2];
#pragma unroll
      for (int q = 0; q < 2; ++q) {
        int ii = i + q;
        float rr = sigmf(r0a[ii] + brz0[0]);
        float zg = sigmf(z0a[ii] + brz0[1]);
        float nn = tanhf_fast(ni0[ii] + bin0 + rr * (nh0[ii] + bhn0));
        hn[q] = nn + zg * (h0reg[ii] - nn);
        h0reg[ii] = hn[q];
      }
      unsigned pk = f2bf_pk(hn[0], hn[1]);
      int m = quad * 4 + i;
      sh_h0[nxt][m * 136 + c]       = (u16)pk;
      sh_h0[nxt][(m + 1) * 136 + c] = (u16)(pk >> 16);
    }
  }

  // ---- epilogue: L1(63); h0(63)@buf1, h1(62)@buf1
  __syncthreads();
  {
    s16x8 ah0[4], ah1[4];
#pragma unroll
    for (int kk = 0; kk < 4; ++kk) {
      ah0[kk] = *(const s16x8*)(sh_h0[1] + l16 * 136 + kk * 32 + quad * 8);
      ah1[kk] = *(const s16x8*)(sh_h1[1] + l16 * 136 + kk * 32 + quad * 8);
    }
    f32x4 r1a, z1a, ni1, nh1;
    r1a = mfma16(ah0[0], B1ih[0][0], zz4);
    z1a = mfma16(ah0[0], B1ih[1][0], zz4);
    ni1 = mfma16(ah0[0], B1ih[2][0], zz4);
    nh1 = mfma16(ah1[0], B1hh[2][0], zz4);
#pragma unroll
    for (int kk = 1; kk < 4; ++kk) {
      r1a = mfma16(ah0[kk], B1ih[0][kk], r1a);
      z1a = mfma16(ah0[kk], B1ih[1][kk], z1a);
      ni1 = mfma16(ah0[kk], B1ih[2][kk], ni1);
      nh1 = mfma16(ah1[kk], B1hh[2][kk], nh1);
    }
#pragma unroll
    for (int kk = 0; kk < 4; ++kk) {
      r1a = mfma16(ah1[kk], B1hh[0][kk], r1a);
      z1a = mfma16(ah1[kk], B1hh[1][kk], z1a);
    }
#pragma unroll
    for (int i = 0; i < 4; ++i) {
      int m = quad * 4 + i;
      float rr = sigmf(r1a[i] + brz1[0]);
      float zg = sigmf(z1a[i] + brz1[1]);
      float nn = tanhf_fast(ni1[i] + bin1 + rr * (nh1[i] + bhn1));
      float hnew = nn + zg * (h1reg[i] - nn);
      g_out[(size_t)(r0 + m) * 128 + c] = hnew;
    }
  }
}

// ---------------------------------------------------------------- row norms + bf16
__global__ void norm_cvt(const float* __restrict__ src, u16* __restrict__ dst,
                         float* __restrict__ rn)
{
  const int tid = threadIdx.x;
  const int wv = tid >> 6, l = tid & 63;
  const int row = blockIdx.x * 4 + wv;
  float2 f2 = *(const float2*)(src + (size_t)row * 128 + l * 2);
  float s = f2.x * f2.x + f2.y * f2.y;
#pragma unroll
  for (int off = 32; off >= 1; off >>= 1) s += __shfl_xor(s, off);
  ushort2 p; p.x = f2bf(f2.x); p.y = f2bf(f2.y);
  *(ushort2*)(dst + (size_t)row * 128 + l * 2) = p;
  if (l == 0) rn[row] = (s == 0.f) ? 0.f : rsqrtf(s);
}

// ---------------------------------------------------------------- cos-sim GEMM
template<int MODE>
__launch_bounds__(256, 1)
__global__ void cos_gemm(const u16* __restrict__ A, const u16* __restrict__ B,
                         const float* __restrict__ rnA, const float* __restrict__ rnB,
                         float* __restrict__ C, u16* __restrict__ E,
                         float* __restrict__ colsum)
{
  __shared__ u16 shA[128 * 136];
  __shared__ u16 shB[128 * 136];
  const int tid = threadIdx.x;
  const int l = tid & 63, wv = tid >> 6;
  const int quad = l >> 4, l16 = l & 15;
  const int i0 = blockIdx.y * 128, j0 = blockIdx.x * 128;
  {
    int r = tid >> 1, half = tid & 1;
    const int4* sa = (const int4*)(A + (size_t)(i0 + r) * 128 + half * 64);
    int4* da = (int4*)(shA + r * 136 + half * 64);
    const int4* sb = (const int4*)(B + (size_t)(j0 + r) * 128 + half * 64);
    int4* db = (int4*)(shB + r * 136 + half * 64);
#pragma unroll
    for (int q = 0; q < 8; ++q) { da[q] = sa[q]; db[q] = sb[q]; }
  }
  __syncthreads();
  const int wm = wv >> 1, wn = wv & 1;
  f32x4 acc[4][4];
  const f32x4 zz4 = {0.f, 0.f, 0.f, 0.f};
#pragma unroll
  for (int a = 0; a < 4; ++a)
#pragma unroll
    for (int b = 0; b < 4; ++b) acc[a][b] = zz4;
#pragma unroll
  for (int kk = 0; kk < 4; ++kk) {
    s16x8 af[4], bfr[4];
#pragma unroll
    for (int mt = 0; mt < 4; ++mt)
      af[mt] = *(const s16x8*)(shA + (wm * 64 + mt * 16 + l16) * 136 + kk * 32 + quad * 8);
#pragma unroll
    for (int nt = 0; nt < 4; ++nt)
      bfr[nt] = *(const s16x8*)(shB + (wn * 64 + nt * 16 + l16) * 136 + kk * 32 + quad * 8);
#pragma unroll
    for (int mt = 0; mt < 4; ++mt)
#pragma unroll
      for (int nt = 0; nt < 4; ++nt) acc[mt][nt] = mfma16(af[mt], bfr[nt], acc[mt][nt]);
  }
  float ra[4][4];
#pragma unroll
  for (int mt = 0; mt < 4; ++mt)
#pragma unroll
    for (int i = 0; i < 4; ++i) ra[mt][i] = rnA[i0 + wm * 64 + mt * 16 + quad * 4 + i];
#pragma unroll
  for (int nt = 0; nt < 4; ++nt) {
    int col = j0 + wn * 64 + nt * 16 + l16;
    float rb = rnB[col];
    float psum = 0.f;
#pragma unroll
    for (int mt = 0; mt < 4; ++mt)
#pragma unroll
      for (int i = 0; i < 4; ++i) {
        int row = i0 + wm * 64 + mt * 16 + quad * 4 + i;
        float v = acc[mt][nt][i] * ra[mt][i] * rb;
        if constexpr (MODE == 0) {
          C[(size_t)row * 4096 + col] = v;
        } else {
          float e = __expf(v);
          E[(size_t)row * 4096 + col] = f2bf(e);
          psum += e;
        }
      }
    if constexpr (MODE == 1) {
      psum += __shfl_xor(psum, 16);
      psum += __shfl_xor(psum, 32);
      if (quad == 0) atomicAdd(colsum + col, psum);
    }
  }
}

// ---------------------------------------------------------------- topK select (no scatter)
__launch_bounds__(256, 1)
__global__ void topk_select(const float* __restrict__ sim,
                            int* __restrict__ gselj, float* __restrict__ gselv,
                            int* __restrict__ cnt, int* __restrict__ touched)
{
  __shared__ unsigned hist[2048];
  __shared__ u64 cand[3072];
  __shared__ int selj[20];
  __shared__ unsigned ws4[4];
  __shared__ int shb, shcnt;
  const int tid = threadIdx.x;
  const int row = blockIdx.x;
  const int l = tid & 63, wv = tid >> 6;

  for (int i = tid; i < 2048; i += 256) hist[i] = 0;
  if (tid == 0) shcnt = 0;
  __syncthreads();

  unsigned key[4][4];
#pragma unroll
  for (int q = 0; q < 4; ++q) {
    int e0 = (q * 256 + tid) * 4;
    float4 v = *(const float4*)(sim + (size_t)row * 4096 + e0);
    key[q][0] = (e0 + 0 == row) ? 0u : (__float_as_uint(v.x) & 0x7FFFFFFFu);
    key[q][1] = (e0 + 1 == row) ? 0u : (__float_as_uint(v.y) & 0x7FFFFFFFu);
    key[q][2] = (e0 + 2 == row) ? 0u : (__float_as_uint(v.z) & 0x7FFFFFFFu);
    key[q][3] = (e0 + 3 == row) ? 0u : (__float_as_uint(v.w) & 0x7FFFFFFFu);
#pragma unroll
    for (int c = 0; c < 4; ++c) {
      unsigned bin = key[q][c] >> 19; if (bin > 2047u) bin = 2047u;
      atomicAdd(&hist[bin], 1u);
    }
  }
  __syncthreads();

  unsigned s = 0;
#pragma unroll
  for (int j = 0; j < 8; ++j) s += hist[tid * 8 + j];
  unsigned r = s;
#pragma unroll
  for (int off = 1; off < 64; off <<= 1) {
    unsigned o = __shfl_down(r, off);
    if (l + off < 64) r += o;
  }
  if (l == 0) ws4[wv] = r;
  __syncthreads();
  unsigned upper = 0;
  for (int q = wv + 1; q < 4; ++q) upper += ws4[q];
  unsigned excl = upper + (r - s);
  if (excl < 20u && excl + s >= 20u) {
    unsigned cum = excl;
    for (int j = 7; j >= 0; --j) {
      cum += hist[tid * 8 + j];
      if (cum >= 20u) { shb = tid * 8 + j; break; }
    }
  }
  __syncthreads();
  const unsigned b = (unsigned)shb;

#pragma unroll
  for (int q = 0; q < 4; ++q) {
    int e0 = (q * 256 + tid) * 4;
#pragma unroll
    for (int c = 0; c < 4; ++c) {
      unsigned bin = key[q][c] >> 19; if (bin > 2047u) bin = 2047u;
      if (bin >= b) {
        int p = atomicAdd(&shcnt, 1);
        if (p < 3072) cand[p] = ((u64)key[q][c] << 32) | (u64)(4095 - (e0 + c));
      }
    }
  }
  __syncthreads();
  const int C = (shcnt < 3072) ? shcnt : 3072;

  if (wv == 0) {
    for (int it = 0; it < 20; ++it) {
      u64 best = 0ull; int bpos = -1;
      for (int p = l; p < C; p += 64) {
        u64 cv = cand[p];
        if (cv > best) { best = cv; bpos = p; }
      }
      u64 mine = best;
#pragma unroll
      for (int off = 1; off < 64; off <<= 1) {
        u64 o = __shfl_xor(best, off);
        if (o > best) best = o;
      }
      if (mine == best && bpos >= 0 && best != 0ull) cand[bpos] = 0ull;
      if (l == 0) selj[it] = 4095 - (int)(best & 0xFFFull);
    }
  }
  __syncthreads();
  if (tid < 20) {
    int idx = selj[tid];
    float sv = (idx == row) ? 0.f : sim[(size_t)row * 4096 + idx];
    gselj[row * 20 + tid] = idx;
    gselv[row * 20 + tid] = sv;
    atomicAdd(&cnt[idx], 1);
    if (sv != 0.f) atomicOr(touched + idx, 1);
  }
}

// ---------------------------------------------------------------- exclusive scan of cnt[4096]
__launch_bounds__(1024, 1)
__global__ void scan4096(const int* __restrict__ cnt, int* __restrict__ offs,
                         int* __restrict__ cur)
{
  __shared__ int wsum[16];
  const int t = threadIdx.x, l = t & 63, wv = t >> 6;
  int4 c = ((const int4*)cnt)[t];
  int s = c.x + c.y + c.z + c.w;
  int ps = s;
#pragma unroll
  for (int off = 1; off < 64; off <<= 1) {
    int o = __shfl_up(ps, off);
    if (l >= off) ps += o;
  }
  if (l == 63) wsum[wv] = ps;
  __syncthreads();
  if (t == 0) {
    int a = 0;
#pragma unroll
    for (int q = 0; q < 16; ++q) { int x = wsum[q]; wsum[q] = a; a += x; }
  }
  __syncthreads();
  int base = wsum[wv] + (ps - s);
  int4 o4;
  o4.x = base; o4.y = o4.x + c.x; o4.z = o4.y + c.y; o4.w = o4.z + c.z;
  ((int4*)offs)[t] = o4;
  ((int4*)cur)[t] = o4;
}

// ---------------------------------------------------------------- CSR entry scatter
__global__ void scatter_entries(const int* __restrict__ gselj, const float* __restrict__ gselv,
                                int* __restrict__ cur, int* __restrict__ eid,
                                float* __restrict__ ev)
{
  unsigned idx = blockIdx.x * 256 + threadIdx.x;
  unsigned row = idx / 20u;
  int j = gselj[idx]; float v = gselv[idx];
  int pos = atomicAdd(&cur[j], 1);
  eid[pos] = (int)row; ev[pos] = v;
}

// ---------------------------------------------------------------- concept gather + cf fused
__launch_bounds__(128, 1)
__global__ void concept_cf(const int* __restrict__ offs, const int* __restrict__ cnt,
                           const int* __restrict__ eid, const float* __restrict__ ev,
                           const float* __restrict__ g, const float* __restrict__ sim,
                           const int* __restrict__ touched,
                           const float* __restrict__ Whc, const float* __restrict__ bhc,
                           float* __restrict__ cf, u16* __restrict__ cfbf,
                           float* __restrict__ rncf)
{
  __shared__ float shc[128];
  __shared__ float red2[2];
  const int j = blockIdx.x, d = threadIdx.x;
  const int l = d & 63, wv = d >> 6;
  const int off = offs[j], n = cnt[j];
  float acc = 0.f;
  for (int p = 0; p < n; ++p) {
    int i = eid[off + p]; float v = ev[off + p];
    acc += v * g[(size_t)i * 128 + d];
  }
  if (touched[j]) acc += sim[(size_t)j * 4097] * g[(size_t)j * 128 + d];
  float s = acc;
#pragma unroll
  for (int o = 32; o >= 1; o >>= 1) s += __shfl_xor(s, o);
  if (l == 0) red2[wv] = s;
  shc[d] = acc;
  __syncthreads();
  float valid = ((red2[0] + red2[1]) != 0.f) ? 1.f : 0.f;
  float o = bhc[d];
  const float4* wr = (const float4*)(Whc + (size_t)d * 128);
#pragma unroll 8
  for (int q = 0; q < 32; ++q) {
    float4 w4 = wr[q];
    float4 c4 = *((const float4*)shc + q);
    o += c4.x * w4.x + c4.y * w4.y + c4.z * w4.z + c4.w * w4.w;
  }
  float cfv = lrelu(o) * valid;
  cf[(size_t)j * 128 + d] = cfv;
  cfbf[(size_t)j * 128 + d] = f2bf(cfv);
  __syncthreads();
  float nn = cfv * cfv;
#pragma unroll
  for (int of = 32; of >= 1; of >>= 1) nn += __shfl_xor(nn, of);
  if (l == 0) red2[wv] = nn;
  __syncthreads();
  if (d == 0) {
    float q2 = red2[0] + red2[1];
    rncf[j] = (q2 == 0.f) ? 0.f : rsqrtf(q2);
  }
}

// ---------------------------------------------------------------- cfTs[n][c] = bf16(cf[c][n]/Z[c])
__global__ void scale_cfT(const float* __restrict__ cf, const float* __restrict__ colsum,
                          u16* __restrict__ cfTs)
{
  int idx = blockIdx.x * 256 + threadIdx.x;
  int n = idx >> 12, c = idx & 4095;
  float rz = __builtin_amdgcn_rcpf(colsum[c]);
  cfTs[idx] = f2bf(cf[(size_t)c * 128 + n] * rz);
}

// ---------------------------------------------------------------- hs_pre = E @ cfTs.T
__launch_bounds__(256, 1)
__global__ void attn_cf(const u16* __restrict__ attn, const u16* __restrict__ cfT,
                        float* __restrict__ hs_pre)
{
  __shared__ u16 shw[16 * 136];
  const int tid = threadIdx.x;
  const int l = tid & 63, wv = tid >> 6;
  const int quad = l >> 4, l16 = l & 15;
  const int r0 = blockIdx.x * 16;
  f32x4 acc[2];
  const f32x4 zz4 = {0.f, 0.f, 0.f, 0.f};
  acc[0] = zz4; acc[1] = zz4;
  for (int kc = 0; kc < 32; ++kc) {
    if (kc) __syncthreads();
    {
      int r = tid >> 4, seg = tid & 15;
      *(int4*)(shw + r * 136 + seg * 8) =
        *(const int4*)(attn + (size_t)(r0 + r) * 4096 + kc * 128 + seg * 8);
    }
    __syncthreads();
#pragma unroll
    for (int kk = 0; kk < 4; ++kk) {
      s16x8 a = *(const s16x8*)(shw + l16 * 136 + kk * 32 + quad * 8);
#pragma unroll
      for (int nt = 0; nt < 2; ++nt) {
        int n = wv * 32 + nt * 16 + l16;
        s16x8 b = *(const s16x8*)(cfT + (size_t)n * 4096 + kc * 128 + kk * 32 + quad * 8);
        acc[nt] = mfma16(a, b, acc[nt]);
      }
    }
  }
#pragma unroll
  for (int nt = 0; nt < 2; ++nt)
#pragma unroll
    for (int i = 0; i < 4; ++i) {
      int row = r0 + quad * 4 + i;
      int col = wv * 32 + nt * 16 + l16;
      hs_pre[(size_t)row * 128 + col] = acc[nt][i];
    }
}

// ---------------------------------------------------------------- head: MFMA chain
__launch_bounds__(256, 1)
__global__ void head_kernel(const float* __restrict__ hs_pre, const float* __restrict__ g,
                            const u16* __restrict__ whs, const u16* __restrict__ wfore,
                            const u16* __restrict__ wback, const u16* __restrict__ windi,
                            const float* __restrict__ b_hs, const float* __restrict__ b_fore,
                            const float* __restrict__ b_back, const float* __restrict__ b_indi,
                            const float* __restrict__ W_out, const float* __restrict__ b_out,
                            float* __restrict__ outp)
{
  __shared__ u16 bufin[16 * 136];
  __shared__ u16 bufB[16 * 136];
  __shared__ float bufF[16 * 132];
  __shared__ float shWout[128];
  const int tid = threadIdx.x;
  const int l = tid & 63, wv = tid >> 6;
  const int quad = l >> 4, l16 = l & 15;
  const int r0 = blockIdx.x * 16;
  const f32x4 zz4 = {0.f, 0.f, 0.f, 0.f};

  if (tid < 128) shWout[tid] = W_out[tid];
  for (int idx = tid; idx < 2048; idx += 256) {
    int j = idx >> 7, n = idx & 127;
    bufin[j * 136 + n] = f2bf(hs_pre[(size_t)(r0 + j) * 128 + n]);
  }
  __syncthreads();
  {
    s16x8 a[4];
#pragma unroll
    for (int kk = 0; kk < 4; ++kk)
      a[kk] = *(const s16x8*)(bufin + l16 * 136 + kk * 32 + quad * 8);
    f32x4 acc[2]; acc[0] = zz4; acc[1] = zz4;
#pragma unroll
    for (int nt = 0; nt < 2; ++nt) {
      int n = wv * 32 + nt * 16 + l16;
#pragma unroll
      for (int kk = 0; kk < 4; ++kk)
        acc[nt] = mfma16(a[kk], *(const s16x8*)(whs + n * 128 + kk * 32 + quad * 8), acc[nt]);
    }
#pragma unroll
    for (int nt = 0; nt < 2; ++nt) {
      int n = wv * 32 + nt * 16 + l16;
      float bb = b_hs[n];
#pragma unroll
      for (int i = 0; i < 4; ++i)
        bufB[(quad * 4 + i) * 136 + n] = f2bf(lrelu(acc[nt][i] + bb));
    }
  }
  __syncthreads();
  {
    s16x8 a[4];
#pragma unroll
    for (int kk = 0; kk < 4; ++kk)
      a[kk] = *(const s16x8*)(bufB + l16 * 136 + kk * 32 + quad * 8);
    f32x4 aF[2], aB[2]; aF[0] = zz4; aF[1] = zz4; aB[0] = zz4; aB[1] = zz4;
#pragma unroll
    for (int nt = 0; nt < 2; ++nt) {
      int n = wv * 32 + nt * 16 + l16;
#pragma unroll
      for (int kk = 0; kk < 4; ++kk) {
        aF[nt] = mfma16(a[kk], *(const s16x8*)(wfore + n * 128 + kk * 32 + quad * 8), aF[nt]);
        aB[nt] = mfma16(a[kk], *(const s16x8*)(wback + n * 128 + kk * 32 + quad * 8), aB[nt]);
      }
    }
#pragma unroll
    for (int nt = 0; nt < 2; ++nt) {
      int n = wv * 32 + nt * 16 + l16;
      float bf_ = b_fore[n], bb_ = b_back[n];
#pragma unroll
      for (int i = 0; i < 4; ++i) {
        int m = quad * 4 + i;
        bufF[m * 132 + n] = lrelu(aF[nt][i] + bf_);
        float back = lrelu(aB[nt][i] + bb_);
        float gv = g[(size_t)(r0 + m) * 128 + n];
        bufin[m * 136 + n] = f2bf(gv - back);
      }
    }
  }
  __syncthreads();
  {
    s16x8 a[4];
#pragma unroll
    for (int kk = 0; kk < 4; ++kk)
      a[kk] = *(const s16x8*)(bufin + l16 * 136 + kk * 32 + quad * 8);
    f32x4 acc[2]; acc[0] = zz4; acc[1] = zz4;
#pragma unroll
    for (int nt = 0; nt < 2; ++nt) {
      int n = wv * 32 + nt * 16 + l16;
#pragma unroll
      for (int kk = 0; kk < 4; ++kk)
        acc[nt] = mfma16(a[kk], *(const s16x8*)(windi + n * 128 + kk * 32 + quad * 8), acc[nt]);
    }
#pragma unroll
    for (int nt = 0; nt < 2; ++nt) {
      int n = wv * 32 + nt * 16 + l16;
      float bi_ = b_indi[n];
#pragma unroll
      for (int i = 0; i < 4; ++i)
        bufF[(quad * 4 + i) * 132 + n] += lrelu(acc[nt][i] + bi_);
    }
  }
  __syncthreads();
  if (tid < 16) {
    float s = b_out[0];
    const float* fr = bufF + tid * 132;
    for (int n = 0; n < 128; ++n) s += fr[n] * shWout[n];
    outp[r0 + tid] = s;
  }
}

// ---------------------------------------------------------------- workspace layout
static const size_t OFF_A       = 0;             // 67,108,864  sim fp32
static const size_t OFF_ATTN    = 67108864;      // 33,554,432  attn numerator bf16
static const size_t OFF_G       = 100663296;
static const size_t OFF_GBF     = 102760448;
static const size_t OFF_RNG     = 103809024;
static const size_t OFF_SELJ    = 103825408;
static const size_t OFF_SELV    = 104153088;
static const size_t OFF_EID     = 104480768;
static const size_t OFF_EV      = 104808448;
static const size_t OFF_CNT     = 105136128;
static const size_t OFF_TOUCH   = 105152512;
static const size_t OFF_COLSUM  = 105168896;
static const size_t OFF_OFFS    = 105185280;
static const size_t OFF_CUR     = 105201664;
static const size_t OFF_CF      = 105218048;
static const size_t OFF_CFBF    = 107315200;
static const size_t OFF_CFTS    = 108363776;
static const size_t OFF_RNCF    = 109412352;
static const size_t OFF_HSPRE   = 109428736;
static const size_t OFF_WB      = 111525888;

extern "C" void kernel_launch(void* const* d_in, const int* in_sizes, int n_in,
                              void* d_out, int out_size, void* d_ws, size_t ws_size,
                              hipStream_t stream)
{
  (void)in_sizes; (void)n_in; (void)out_size; (void)ws_size;
  const float* x      = (const float*)d_in[0];
  const float* Wih0   = (const float*)d_in[1];
  const float* Whh0   = (const float*)d_in[2];
  const float* bih0   = (const float*)d_in[3];
  const float* bhh0   = (const float*)d_in[4];
  const float* Wih1   = (const float*)d_in[5];
  const float* Whh1   = (const float*)d_in[6];
  const float* bih1   = (const float*)d_in[7];
  const float* bhh1   = (const float*)d_in[8];
  const float* W_hc   = (const float*)d_in[9];
  const float* b_hc   = (const float*)d_in[10];
  const float* W_hs   = (const float*)d_in[11];
  const float* b_hs   = (const float*)d_in[12];
  const float* W_fore = (const float*)d_in[13];
  const float* b_fore = (const float*)d_in[14];
  const float* W_back = (const float*)d_in[15];
  const float* b_back = (const float*)d_in[16];
  const float* W_indi = (const float*)d_in[17];
  const float* b_indi = (const float*)d_in[18];
  const float* W_out  = (const float*)d_in[19];
  const float* b_out  = (const float*)d_in[20];

  char* ws = (char*)d_ws;
  float* simbuf  = (float*)(ws + OFF_A);
  u16*   attnb   = (u16*)(ws + OFF_ATTN);
  float* gbuf    = (float*)(ws + OFF_G);
  u16*   gbf     = (u16*)(ws + OFF_GBF);
  float* rng     = (float*)(ws + OFF_RNG);
  int*   gselj   = (int*)(ws + OFF_SELJ);
  float* gselv   = (float*)(ws + OFF_SELV);
  int*   eid     = (int*)(ws + OFF_EID);
  float* ev      = (float*)(ws + OFF_EV);
  int*   cntb    = (int*)(ws + OFF_CNT);
  int*   touched = (int*)(ws + OFF_TOUCH);
  float* colsum  = (float*)(ws + OFF_COLSUM);
  int*   offsb   = (int*)(ws + OFF_OFFS);
  int*   curb    = (int*)(ws + OFF_CUR);
  float* cf      = (float*)(ws + OFF_CF);
  u16*   cfbf    = (u16*)(ws + OFF_CFBF);
  u16*   cfTs    = (u16*)(ws + OFF_CFTS);
  float* rncf    = (float*)(ws + OFF_RNCF);
  float* hs_pre  = (float*)(ws + OFF_HSPRE);
  u16*   wsB     = (u16*)(ws + OFF_WB);
  u16 *wih0b = wsB, *whh0b = wsB + 12288, *wih1b = wsB + 61440, *whh1b = wsB + 110592;
  u16 *whsb = wsB + 159744, *wforeb = wsB + 176128, *wbackb = wsB + 192512, *windib = wsB + 208896;

  cvt_all<<<880, 256, 0, stream>>>(Wih0, Whh0, Wih1, Whh1, W_hs, W_fore, W_back, W_indi, wsB);

  gru_fused<<<256, 512, 0, stream>>>(x, wih0b, whh0b, bih0, bhh0,
                                     wih1b, whh1b, bih1, bhh1, gbuf);

  norm_cvt<<<1024, 256, 0, stream>>>(gbuf, gbf, rng);
  cos_gemm<0><<<dim3(32, 32), 256, 0, stream>>>(gbf, gbf, rng, rng, simbuf,
                                                (u16*)nullptr, (float*)nullptr);

  hipMemsetAsync(ws + OFF_CNT, 0, 49152, stream);
  topk_select<<<4096, 256, 0, stream>>>(simbuf, gselj, gselv, cntb, touched);
  scan4096<<<1, 1024, 0, stream>>>(cntb, offsb, curb);
  scatter_entries<<<320, 256, 0, stream>>>(gselj, gselv, curb, eid, ev);
  concept_cf<<<4096, 128, 0, stream>>>(offsb, cntb, eid, ev, gbuf, simbuf, touched,
                                       W_hc, b_hc, cf, cfbf, rncf);

  cos_gemm<1><<<dim3(32, 32), 256, 0, stream>>>(gbf, cfbf, rng, rncf, (float*)nullptr,
                                                attnb, colsum);
  scale_cfT<<<2048, 256, 0, stream>>>(cf, colsum, cfTs);
  attn_cf<<<256, 256, 0, stream>>>(attnb, cfTs, hs_pre);

  head_kernel<<<256, 256, 0, stream>>>(hs_pre, gbuf, whsb, wforeb, wbackb, windib,
                                       b_hs, b_fore, b_back, b_indi, W_out, b_out,
                                       (float*)d_out);
}

// Round 9
// 429.001 us; speedup vs baseline: 1.0433x; 1.0050x over previous
//
#include <hip/hip_runtime.h>
#include <hip/hip_bf16.h>

// SGA_75531294867605 — GRU x2 -> cos-sim topK concept graph -> softmax attention head.
// R9: GRU register fix — __launch_bounds__(512,2) capped VGPRs at 128 while ~200
//     are live (B-frags 156 + accs), forcing AGPR spill shuttles (v_accvgpr_*)
//     on the VALU pipe = the unexplained ~50% VALUBusy. Grid=256 is 1 block/CU
//     anyway, so declare (512,1) -> 256 VGPR budget. Also unroll t-loop by 2
//     with compile-time buffer parity (loop-invariant LDS addresses).

typedef float f32x4 __attribute__((ext_vector_type(4)));
typedef short s16x8 __attribute__((ext_vector_type(8)));
typedef unsigned short u16;
typedef unsigned long long u64;

#define DEVFN static __device__ __forceinline__

DEVFN u16 f2bf(float f) {
  union { float f; unsigned u; } v; v.f = f;
  return (u16)((v.u + 0x7FFFu + ((v.u >> 16) & 1u)) >> 16);  // RNE
}

DEVFN unsigned f2bf_pk(float lo, float hi) {   // low16=bf16(lo), high16=bf16(hi)
  union { __hip_bfloat162 h; unsigned u; } p;
  p.h = __float22bfloat162_rn(make_float2(lo, hi));
  return p.u;
}

DEVFN f32x4 mfma16(s16x8 a, s16x8 b, f32x4 c) {
  return __builtin_amdgcn_mfma_f32_16x16x32_bf16(a, b, c, 0, 0, 0);
}

DEVFN float sigmf(float x) { return __builtin_amdgcn_rcpf(1.f + __expf(-x)); }
DEVFN float tanhf_fast(float x) {
  float e = __expf(2.f * x);
  return 1.f - 2.f * __builtin_amdgcn_rcpf(e + 1.f);
}
DEVFN float lrelu(float v) { return v > 0.f ? v : 0.2f * v; }

// ---------------------------------------------------------------- all-weights fp32->bf16
__global__ void cvt_all(const float* __restrict__ w0, const float* __restrict__ w1,
                        const float* __restrict__ w2, const float* __restrict__ w3,
                        const float* __restrict__ w4, const float* __restrict__ w5,
                        const float* __restrict__ w6, const float* __restrict__ w7,
                        u16* __restrict__ dst) {
  int i = blockIdx.x * 256 + threadIdx.x;
  if (i >= 225280) return;
  float v;
  if      (i < 12288)  v = w0[i];
  else if (i < 61440)  v = w1[i - 12288];
  else if (i < 110592) v = w2[i - 61440];
  else if (i < 159744) v = w3[i - 110592];
  else if (i < 176128) v = w4[i - 159744];
  else if (i < 192512) v = w5[i - 176128];
  else if (i < 208896) v = w6[i - 192512];
  else                 v = w7[i - 208896];
  dst[i] = f2bf(v);
}

// ---------------------------------------------------------------- fused 2-layer GRU
__launch_bounds__(512, 1)
__global__ void gru_fused(const float* __restrict__ x,
                          const u16* __restrict__ Wih0, const u16* __restrict__ Whh0,
                          const float* __restrict__ bih0, const float* __restrict__ bhh0,
                          const u16* __restrict__ Wih1, const u16* __restrict__ Whh1,
                          const float* __restrict__ bih1, const float* __restrict__ bhh1,
                          float* __restrict__ g_out)
{
  const int tid  = threadIdx.x;
  const int w    = tid >> 6;
  const int l    = tid & 63;
  const int quad = l >> 4;
  const int l16  = l & 15;
  const int r0   = blockIdx.x * 16;
  const int c    = w * 16 + l16;

  __shared__ u16 sh_x[2][16 * 40];
  __shared__ u16 sh_h0[2][16 * 136];
  __shared__ u16 sh_h1[2][16 * 136];

  s16x8 B0ih[3];
  s16x8 B0hh[3][4];
  s16x8 B1ih[3][4];
  s16x8 B1hh[3][4];
  float brz0[2], bin0, bhn0, brz1[2], bin1, bhn1;
  {
    int j0g = c, j1g = 128 + c, j2g = 256 + c;
    brz0[0] = bih0[j0g] + bhh0[j0g];  brz0[1] = bih0[j1g] + bhh0[j1g];
    bin0 = bih0[j2g];  bhn0 = bhh0[j2g];
    brz1[0] = bih1[j0g] + bhh1[j0g];  brz1[1] = bih1[j1g] + bhh1[j1g];
    bin1 = bih1[j2g];  bhn1 = bhh1[j2g];
  }
#pragma unroll
  for (int g = 0; g < 3; ++g) {
    int j = g * 128 + c;
    B0ih[g] = *(const s16x8*)(Wih0 + j * 32 + quad * 8);
#pragma unroll
    for (int kk = 0; kk < 4; ++kk) {
      B0hh[g][kk] = *(const s16x8*)(Whh0 + j * 128 + kk * 32 + quad * 8);
      B1ih[g][kk] = *(const s16x8*)(Wih1 + j * 128 + kk * 32 + quad * 8);
      B1hh[g][kk] = *(const s16x8*)(Whh1 + j * 128 + kk * 32 + quad * 8);
    }
  }
  float h0reg[4] = {0.f, 0.f, 0.f, 0.f};
  float h1reg[4] = {0.f, 0.f, 0.f, 0.f};
  for (int idx = tid; idx < 16 * 136; idx += 512) sh_h1[0][idx] = 0;

  const int xr = tid >> 5, xc = tid & 31;
  const float* xrow = x + (size_t)(r0 + xr) * 2048 + xc;
  float xpre = xrow[0];                  // x(0)
  sh_x[0][xr * 40 + xc] = f2bf(xpre);
  xpre = xrow[32];                       // x(1)
  __syncthreads();

  const f32x4 zz4 = {0.f, 0.f, 0.f, 0.f};
  // ---- prologue: h0(0) from x(0), h0(-1)=0
  {
    s16x8 ax = *(const s16x8*)(sh_x[0] + l16 * 40 + quad * 8);
    f32x4 ai[3];
#pragma unroll
    for (int g = 0; g < 3; ++g) ai[g] = mfma16(ax, B0ih[g], zz4);
#pragma unroll
    for (int i = 0; i < 4; i += 2) {
      float hn[2];
#pragma unroll
      for (int q = 0; q < 2; ++q) {
        int ii = i + q;
        float rr = sigmf(ai[0][ii] + brz0[0]);
        float zg = sigmf(ai[1][ii] + brz0[1]);
        float nn = tanhf_fast(ai[2][ii] + bin0 + rr * bhn0);
        hn[q] = nn - zg * nn;
        h0reg[ii] = hn[q];
      }
      unsigned pk = f2bf_pk(hn[0], hn[1]);
      int m = quad * 4 + i;
      sh_h0[0][m * 136 + c]       = (u16)pk;
      sh_h0[0][(m + 1) * 136 + c] = (u16)(pk >> 16);
    }
  }

  // ---- main: phase t computes L1(t) + L0(t+1); unrolled x2, compile-time parity
#define GRU_STEP(T, CUR, NXT)                                                     \
  {                                                                               \
    sh_x[NXT][xr * 40 + xc] = f2bf(xpre);                                         \
    __syncthreads();                                                              \
    s16x8 ah0[4], ah1[4];                                                         \
    _Pragma("unroll")                                                             \
    for (int kk = 0; kk < 4; ++kk) {                                              \
      ah0[kk] = *(const s16x8*)(sh_h0[CUR] + l16 * 136 + kk * 32 + quad * 8);     \
      ah1[kk] = *(const s16x8*)(sh_h1[CUR] + l16 * 136 + kk * 32 + quad * 8);     \
    }                                                                             \
    s16x8 ax = *(const s16x8*)(sh_x[NXT] + l16 * 40 + quad * 8);                  \
    if ((T) <= 61) xpre = xrow[((T) + 2) * 32];                                   \
    f32x4 r1a, z1a, ni1, nh1, r0a, z0a, ni0, nh0;                                 \
    r1a = mfma16(ah0[0], B1ih[0][0], zz4);                                        \
    z1a = mfma16(ah0[0], B1ih[1][0], zz4);                                        \
    ni1 = mfma16(ah0[0], B1ih[2][0], zz4);                                        \
    nh1 = mfma16(ah1[0], B1hh[2][0], zz4);                                        \
    r0a = mfma16(ax, B0ih[0], zz4);                                               \
    z0a = mfma16(ax, B0ih[1], zz4);                                               \
    ni0 = mfma16(ax, B0ih[2], zz4);                                               \
    nh0 = mfma16(ah0[0], B0hh[2][0], zz4);                                        \
    _Pragma("unroll")                                                             \
    for (int kk = 1; kk < 4; ++kk) {                                              \
      r1a = mfma16(ah0[kk], B1ih[0][kk], r1a);                                    \
      z1a = mfma16(ah0[kk], B1ih[1][kk], z1a);                                    \
      ni1 = mfma16(ah0[kk], B1ih[2][kk], ni1);                                    \
      nh1 = mfma16(ah1[kk], B1hh[2][kk], nh1);                                    \
      nh0 = mfma16(ah0[kk], B0hh[2][kk], nh0);                                    \
    }                                                                             \
    _Pragma("unroll")                                                             \
    for (int kk = 0; kk < 4; ++kk) {                                              \
      r1a = mfma16(ah1[kk], B1hh[0][kk], r1a);                                    \
      z1a = mfma16(ah1[kk], B1hh[1][kk], z1a);                                    \
      r0a = mfma16(ah0[kk], B0hh[0][kk], r0a);                                    \
      z0a = mfma16(ah0[kk], B0hh[1][kk], z0a);                                    \
    }                                                                             \
    _Pragma("unroll")                                                             \
    for (int i = 0; i < 4; i += 2) {                                              \
      float hn[2];                                                                \
      _Pragma("unroll")                                                           \
      for (int q = 0; q < 2; ++q) {                                               \
        int ii = i + q;                                                           \
        float rr = sigmf(r1a[ii] + brz1[0]);                                      \
        float zg = sigmf(z1a[ii] + brz1[1]);                                      \
        float nn = tanhf_fast(ni1[ii] + bin1 + rr * (nh1[ii] + bhn1));            \
        hn[q] = nn + zg * (h1reg[ii] - nn);                                       \
        h1reg[ii] = hn[q];                                                        \
      }                                                                           \
      unsigned pk = f2bf_pk(hn[0], hn[1]);                                        \
      int m = quad * 4 + i;                                                       \
      sh_h1[NXT][m * 136 + c]       = (u16)pk;                                    \
      sh_h1[NXT][(m + 1) * 136 + c] = (u16)(pk >> 16);                            \
    }                                                                             \
    _Pragma("unroll")                                                             \
    for (int i = 0; i < 4; i += 2) {                                              \
      float hn[2];                                                                \
      _Pragma("unroll")                                                           \
      for (int q = 0; q < 2; ++q) {                                               \
        int ii = i + q;                                                           \
        float rr = sigmf(r0a[ii] + brz0[0]);                                      \
        float zg = sigmf(z0a[ii] + brz0[1]);                                      \
        float nn = tanhf_fast(ni0[ii] + bin0 + rr * (nh0[ii] + bhn0));            \
        hn[q] = nn + zg * (h0reg[ii] - nn);                                       \
        h0reg[ii] = hn[q];                                                        \
      }                                                                           \
      unsigned pk = f2bf_pk(hn[0], hn[1]);                                        \
      int m = quad * 4 + i;                                                       \
      sh_h0[NXT][m * 136 + c]       = (u16)pk;                                    \
      sh_h0[NXT][(m + 1) * 136 + c] = (u16)(pk >> 16);                            \
    }                                                                             \
  }

  for (int t2 = 0; t2 < 31; ++t2) {
    int t = t2 * 2;
    GRU_STEP(t, 0, 1);
    GRU_STEP(t + 1, 1, 0);
  }
  GRU_STEP(62, 0, 1);   // t = 62
#undef GRU_STEP

  // ---- epilogue: L1(63); h0(63)@buf1, h1(62)@buf1
  __syncthreads();
  {
    s16x8 ah0[4], ah1[4];
#pragma unroll
    for (int kk = 0; kk < 4; ++kk) {
      ah0[kk] = *(const s16x8*)(sh_h0[1] + l16 * 136 + kk * 32 + quad * 8);
      ah1[kk] = *(const s16x8*)(sh_h1[1] + l16 * 136 + kk * 32 + quad * 8);
    }
    f32x4 r1a, z1a, ni1, nh1;
    r1a = mfma16(ah0[0], B1ih[0][0], zz4);
    z1a = mfma16(ah0[0], B1ih[1][0], zz4);
    ni1 = mfma16(ah0[0], B1ih[2][0], zz4);
    nh1 = mfma16(ah1[0], B1hh[2][0], zz4);
#pragma unroll
    for (int kk = 1; kk < 4; ++kk) {
      r1a = mfma16(ah0[kk], B1ih[0][kk], r1a);
      z1a = mfma16(ah0[kk], B1ih[1][kk], z1a);
      ni1 = mfma16(ah0[kk], B1ih[2][kk], ni1);
      nh1 = mfma16(ah1[kk], B1hh[2][kk], nh1);
    }
#pragma unroll
    for (int kk = 0; kk < 4; ++kk) {
      r1a = mfma16(ah1[kk], B1hh[0][kk], r1a);
      z1a = mfma16(ah1[kk], B1hh[1][kk], z1a);
    }
#pragma unroll
    for (int i = 0; i < 4; ++i) {
      int m = quad * 4 + i;
      float rr = sigmf(r1a[i] + brz1[0]);
      float zg = sigmf(z1a[i] + brz1[1]);
      float nn = tanhf_fast(ni1[i] + bin1 + rr * (nh1[i] + bhn1));
      float hnew = nn + zg * (h1reg[i] - nn);
      g_out[(size_t)(r0 + m) * 128 + c] = hnew;
    }
  }
}

// ---------------------------------------------------------------- row norms + bf16
__global__ void norm_cvt(const float* __restrict__ src, u16* __restrict__ dst,
                         float* __restrict__ rn)
{
  const int tid = threadIdx.x;
  const int wv = tid >> 6, l = tid & 63;
  const int row = blockIdx.x * 4 + wv;
  float2 f2 = *(const float2*)(src + (size_t)row * 128 + l * 2);
  float s = f2.x * f2.x + f2.y * f2.y;
#pragma unroll
  for (int off = 32; off >= 1; off >>= 1) s += __shfl_xor(s, off);
  ushort2 p; p.x = f2bf(f2.x); p.y = f2bf(f2.y);
  *(ushort2*)(dst + (size_t)row * 128 + l * 2) = p;
  if (l == 0) rn[row] = (s == 0.f) ? 0.f : rsqrtf(s);
}

// ---------------------------------------------------------------- cos-sim GEMM
template<int MODE>
__launch_bounds__(256, 1)
__global__ void cos_gemm(const u16* __restrict__ A, const u16* __restrict__ B,
                         const float* __restrict__ rnA, const float* __restrict__ rnB,
                         float* __restrict__ C, u16* __restrict__ E,
                         float* __restrict__ colsum)
{
  __shared__ u16 shA[128 * 136];
  __shared__ u16 shB[128 * 136];
  const int tid = threadIdx.x;
  const int l = tid & 63, wv = tid >> 6;
  const int quad = l >> 4, l16 = l & 15;
  const int i0 = blockIdx.y * 128, j0 = blockIdx.x * 128;
  {
    int r = tid >> 1, half = tid & 1;
    const int4* sa = (const int4*)(A + (size_t)(i0 + r) * 128 + half * 64);
    int4* da = (int4*)(shA + r * 136 + half * 64);
    const int4* sb = (const int4*)(B + (size_t)(j0 + r) * 128 + half * 64);
    int4* db = (int4*)(shB + r * 136 + half * 64);
#pragma unroll
    for (int q = 0; q < 8; ++q) { da[q] = sa[q]; db[q] = sb[q]; }
  }
  __syncthreads();
  const int wm = wv >> 1, wn = wv & 1;
  f32x4 acc[4][4];
  const f32x4 zz4 = {0.f, 0.f, 0.f, 0.f};
#pragma unroll
  for (int a = 0; a < 4; ++a)
#pragma unroll
    for (int b = 0; b < 4; ++b) acc[a][b] = zz4;
#pragma unroll
  for (int kk = 0; kk < 4; ++kk) {
    s16x8 af[4], bfr[4];
#pragma unroll
    for (int mt = 0; mt < 4; ++mt)
      af[mt] = *(const s16x8*)(shA + (wm * 64 + mt * 16 + l16) * 136 + kk * 32 + quad * 8);
#pragma unroll
    for (int nt = 0; nt < 4; ++nt)
      bfr[nt] = *(const s16x8*)(shB + (wn * 64 + nt * 16 + l16) * 136 + kk * 32 + quad * 8);
#pragma unroll
    for (int mt = 0; mt < 4; ++mt)
#pragma unroll
      for (int nt = 0; nt < 4; ++nt) acc[mt][nt] = mfma16(af[mt], bfr[nt], acc[mt][nt]);
  }
  float ra[4][4];
#pragma unroll
  for (int mt = 0; mt < 4; ++mt)
#pragma unroll
    for (int i = 0; i < 4; ++i) ra[mt][i] = rnA[i0 + wm * 64 + mt * 16 + quad * 4 + i];
#pragma unroll
  for (int nt = 0; nt < 4; ++nt) {
    int col = j0 + wn * 64 + nt * 16 + l16;
    float rb = rnB[col];
    float psum = 0.f;
#pragma unroll
    for (int mt = 0; mt < 4; ++mt)
#pragma unroll
      for (int i = 0; i < 4; ++i) {
        int row = i0 + wm * 64 + mt * 16 + quad * 4 + i;
        float v = acc[mt][nt][i] * ra[mt][i] * rb;
        if constexpr (MODE == 0) {
          C[(size_t)row * 4096 + col] = v;
        } else {
          float e = __expf(v);
          E[(size_t)row * 4096 + col] = f2bf(e);
          psum += e;
        }
      }
    if constexpr (MODE == 1) {
      psum += __shfl_xor(psum, 16);
      psum += __shfl_xor(psum, 32);
      if (quad == 0) atomicAdd(colsum + col, psum);
    }
  }
}

// ---------------------------------------------------------------- topK select (no scatter)
__launch_bounds__(256, 1)
__global__ void topk_select(const float* __restrict__ sim,
                            int* __restrict__ gselj, float* __restrict__ gselv,
                            int* __restrict__ cnt, int* __restrict__ touched)
{
  __shared__ unsigned hist[2048];
  __shared__ u64 cand[3072];
  __shared__ int selj[20];
  __shared__ unsigned ws4[4];
  __shared__ int shb, shcnt;
  const int tid = threadIdx.x;
  const int row = blockIdx.x;
  const int l = tid & 63, wv = tid >> 6;

  for (int i = tid; i < 2048; i += 256) hist[i] = 0;
  if (tid == 0) shcnt = 0;
  __syncthreads();

  unsigned key[4][4];
#pragma unroll
  for (int q = 0; q < 4; ++q) {
    int e0 = (q * 256 + tid) * 4;
    float4 v = *(const float4*)(sim + (size_t)row * 4096 + e0);
    key[q][0] = (e0 + 0 == row) ? 0u : (__float_as_uint(v.x) & 0x7FFFFFFFu);
    key[q][1] = (e0 + 1 == row) ? 0u : (__float_as_uint(v.y) & 0x7FFFFFFFu);
    key[q][2] = (e0 + 2 == row) ? 0u : (__float_as_uint(v.z) & 0x7FFFFFFFu);
    key[q][3] = (e0 + 3 == row) ? 0u : (__float_as_uint(v.w) & 0x7FFFFFFFu);
#pragma unroll
    for (int c = 0; c < 4; ++c) {
      unsigned bin = key[q][c] >> 19; if (bin > 2047u) bin = 2047u;
      atomicAdd(&hist[bin], 1u);
    }
  }
  __syncthreads();

  unsigned s = 0;
#pragma unroll
  for (int j = 0; j < 8; ++j) s += hist[tid * 8 + j];
  unsigned r = s;
#pragma unroll
  for (int off = 1; off < 64; off <<= 1) {
    unsigned o = __shfl_down(r, off);
    if (l + off < 64) r += o;
  }
  if (l == 0) ws4[wv] = r;
  __syncthreads();
  unsigned upper = 0;
  for (int q = wv + 1; q < 4; ++q) upper += ws4[q];
  unsigned excl = upper + (r - s);
  if (excl < 20u && excl + s >= 20u) {
    unsigned cum = excl;
    for (int j = 7; j >= 0; --j) {
      cum += hist[tid * 8 + j];
      if (cum >= 20u) { shb = tid * 8 + j; break; }
    }
  }
  __syncthreads();
  const unsigned b = (unsigned)shb;

#pragma unroll
  for (int q = 0; q < 4; ++q) {
    int e0 = (q * 256 + tid) * 4;
#pragma unroll
    for (int c = 0; c < 4; ++c) {
      unsigned bin = key[q][c] >> 19; if (bin > 2047u) bin = 2047u;
      if (bin >= b) {
        int p = atomicAdd(&shcnt, 1);
        if (p < 3072) cand[p] = ((u64)key[q][c] << 32) | (u64)(4095 - (e0 + c));
      }
    }
  }
  __syncthreads();
  const int C = (shcnt < 3072) ? shcnt : 3072;

  if (wv == 0) {
    for (int it = 0; it < 20; ++it) {
      u64 best = 0ull; int bpos = -1;
      for (int p = l; p < C; p += 64) {
        u64 cv = cand[p];
        if (cv > best) { best = cv; bpos = p; }
      }
      u64 mine = best;
#pragma unroll
      for (int off = 1; off < 64; off <<= 1) {
        u64 o = __shfl_xor(best, off);
        if (o > best) best = o;
      }
      if (mine == best && bpos >= 0 && best != 0ull) cand[bpos] = 0ull;
      if (l == 0) selj[it] = 4095 - (int)(best & 0xFFFull);
    }
  }
  __syncthreads();
  if (tid < 20) {
    int idx = selj[tid];
    float sv = (idx == row) ? 0.f : sim[(size_t)row * 4096 + idx];
    gselj[row * 20 + tid] = idx;
    gselv[row * 20 + tid] = sv;
    atomicAdd(&cnt[idx], 1);
    if (sv != 0.f) atomicOr(touched + idx, 1);
  }
}

// ---------------------------------------------------------------- exclusive scan of cnt[4096]
__launch_bounds__(1024, 1)
__global__ void scan4096(const int* __restrict__ cnt, int* __restrict__ offs,
                         int* __restrict__ cur)
{
  __shared__ int wsum[16];
  const int t = threadIdx.x, l = t & 63, wv = t >> 6;
  int4 c = ((const int4*)cnt)[t];
  int s = c.x + c.y + c.z + c.w;
  int ps = s;
#pragma unroll
  for (int off = 1; off < 64; off <<= 1) {
    int o = __shfl_up(ps, off);
    if (l >= off) ps += o;
  }
  if (l == 63) wsum[wv] = ps;
  __syncthreads();
  if (t == 0) {
    int a = 0;
#pragma unroll
    for (int q = 0; q < 16; ++q) { int x = wsum[q]; wsum[q] = a; a += x; }
  }
  __syncthreads();
  int base = wsum[wv] + (ps - s);
  int4 o4;
  o4.x = base; o4.y = o4.x + c.x; o4.z = o4.y + c.y; o4.w = o4.z + c.z;
  ((int4*)offs)[t] = o4;
  ((int4*)cur)[t] = o4;
}

// ---------------------------------------------------------------- CSR entry scatter
__global__ void scatter_entries(const int* __restrict__ gselj, const float* __restrict__ gselv,
                                int* __restrict__ cur, int* __restrict__ eid,
                                float* __restrict__ ev)
{
  unsigned idx = blockIdx.x * 256 + threadIdx.x;
  unsigned row = idx / 20u;
  int j = gselj[idx]; float v = gselv[idx];
  int pos = atomicAdd(&cur[j], 1);
  eid[pos] = (int)row; ev[pos] = v;
}

// ---------------------------------------------------------------- concept gather + cf fused
__launch_bounds__(128, 1)
__global__ void concept_cf(const int* __restrict__ offs, const int* __restrict__ cnt,
                           const int* __restrict__ eid, const float* __restrict__ ev,
                           const float* __restrict__ g, const float* __restrict__ sim,
                           const int* __restrict__ touched,
                           const float* __restrict__ Whc, const float* __restrict__ bhc,
                           float* __restrict__ cf, u16* __restrict__ cfbf,
                           float* __restrict__ rncf)
{
  __shared__ float shc[128];
  __shared__ float red2[2];
  const int j = blockIdx.x, d = threadIdx.x;
  const int l = d & 63, wv = d >> 6;
  const int off = offs[j], n = cnt[j];
  float acc = 0.f;
  for (int p = 0; p < n; ++p) {
    int i = eid[off + p]; float v = ev[off + p];
    acc += v * g[(size_t)i * 128 + d];
  }
  if (touched[j]) acc += sim[(size_t)j * 4097] * g[(size_t)j * 128 + d];
  float s = acc;
#pragma unroll
  for (int o = 32; o >= 1; o >>= 1) s += __shfl_xor(s, o);
  if (l == 0) red2[wv] = s;
  shc[d] = acc;
  __syncthreads();
  float valid = ((red2[0] + red2[1]) != 0.f) ? 1.f : 0.f;
  float o = bhc[d];
  const float4* wr = (const float4*)(Whc + (size_t)d * 128);
#pragma unroll 8
  for (int q = 0; q < 32; ++q) {
    float4 w4 = wr[q];
    float4 c4 = *((const float4*)shc + q);
    o += c4.x * w4.x + c4.y * w4.y + c4.z * w4.z + c4.w * w4.w;
  }
  float cfv = lrelu(o) * valid;
  cf[(size_t)j * 128 + d] = cfv;
  cfbf[(size_t)j * 128 + d] = f2bf(cfv);
  __syncthreads();
  float nn = cfv * cfv;
#pragma unroll
  for (int of = 32; of >= 1; of >>= 1) nn += __shfl_xor(nn, of);
  if (l == 0) red2[wv] = nn;
  __syncthreads();
  if (d == 0) {
    float q2 = red2[0] + red2[1];
    rncf[j] = (q2 == 0.f) ? 0.f : rsqrtf(q2);
  }
}

// ---------------------------------------------------------------- cfTs[n][c] = bf16(cf[c][n]/Z[c])
__global__ void scale_cfT(const float* __restrict__ cf, const float* __restrict__ colsum,
                          u16* __restrict__ cfTs)
{
  int idx = blockIdx.x * 256 + threadIdx.x;
  int n = idx >> 12, c = idx & 4095;
  float rz = __builtin_amdgcn_rcpf(colsum[c]);
  cfTs[idx] = f2bf(cf[(size_t)c * 128 + n] * rz);
}

// ---------------------------------------------------------------- hs_pre = E @ cfTs.T
__launch_bounds__(256, 1)
__global__ void attn_cf(const u16* __restrict__ attn, const u16* __restrict__ cfT,
                        float* __restrict__ hs_pre)
{
  __shared__ u16 shw[16 * 136];
  const int tid = threadIdx.x;
  const int l = tid & 63, wv = tid >> 6;
  const int quad = l >> 4, l16 = l & 15;
  const int r0 = blockIdx.x * 16;
  f32x4 acc[2];
  const f32x4 zz4 = {0.f, 0.f, 0.f, 0.f};
  acc[0] = zz4; acc[1] = zz4;
  for (int kc = 0; kc < 32; ++kc) {
    if (kc) __syncthreads();
    {
      int r = tid >> 4, seg = tid & 15;
      *(int4*)(shw + r * 136 + seg * 8) =
        *(const int4*)(attn + (size_t)(r0 + r) * 4096 + kc * 128 + seg * 8);
    }
    __syncthreads();
#pragma unroll
    for (int kk = 0; kk < 4; ++kk) {
      s16x8 a = *(const s16x8*)(shw + l16 * 136 + kk * 32 + quad * 8);
#pragma unroll
      for (int nt = 0; nt < 2; ++nt) {
        int n = wv * 32 + nt * 16 + l16;
        s16x8 b = *(const s16x8*)(cfT + (size_t)n * 4096 + kc * 128 + kk * 32 + quad * 8);
        acc[nt] = mfma16(a, b, acc[nt]);
      }
    }
  }
#pragma unroll
  for (int nt = 0; nt < 2; ++nt)
#pragma unroll
    for (int i = 0; i < 4; ++i) {
      int row = r0 + quad * 4 + i;
      int col = wv * 32 + nt * 16 + l16;
      hs_pre[(size_t)row * 128 + col] = acc[nt][i];
    }
}

// ---------------------------------------------------------------- head: MFMA chain
__launch_bounds__(256, 1)
__global__ void head_kernel(const float* __restrict__ hs_pre, const float* __restrict__ g,
                            const u16* __restrict__ whs, const u16* __restrict__ wfore,
                            const u16* __restrict__ wback, const u16* __restrict__ windi,
                            const float* __restrict__ b_hs, const float* __restrict__ b_fore,
                            const float* __restrict__ b_back, const float* __restrict__ b_indi,
                            const float* __restrict__ W_out, const float* __restrict__ b_out,
                            float* __restrict__ outp)
{
  __shared__ u16 bufin[16 * 136];
  __shared__ u16 bufB[16 * 136];
  __shared__ float bufF[16 * 132];
  __shared__ float shWout[128];
  const int tid = threadIdx.x;
  const int l = tid & 63, wv = tid >> 6;
  const int quad = l >> 4, l16 = l & 15;
  const int r0 = blockIdx.x * 16;
  const f32x4 zz4 = {0.f, 0.f, 0.f, 0.f};

  if (tid < 128) shWout[tid] = W_out[tid];
  for (int idx = tid; idx < 2048; idx += 256) {
    int j = idx >> 7, n = idx & 127;
    bufin[j * 136 + n] = f2bf(hs_pre[(size_t)(r0 + j) * 128 + n]);
  }
  __syncthreads();
  {
    s16x8 a[4];
#pragma unroll
    for (int kk = 0; kk < 4; ++kk)
      a[kk] = *(const s16x8*)(bufin + l16 * 136 + kk * 32 + quad * 8);
    f32x4 acc[2]; acc[0] = zz4; acc[1] = zz4;
#pragma unroll
    for (int nt = 0; nt < 2; ++nt) {
      int n = wv * 32 + nt * 16 + l16;
#pragma unroll
      for (int kk = 0; kk < 4; ++kk)
        acc[nt] = mfma16(a[kk], *(const s16x8*)(whs + n * 128 + kk * 32 + quad * 8), acc[nt]);
    }
#pragma unroll
    for (int nt = 0; nt < 2; ++nt) {
      int n = wv * 32 + nt * 16 + l16;
      float bb = b_hs[n];
#pragma unroll
      for (int i = 0; i < 4; ++i)
        bufB[(quad * 4 + i) * 136 + n] = f2bf(lrelu(acc[nt][i] + bb));
    }
  }
  __syncthreads();
  {
    s16x8 a[4];
#pragma unroll
    for (int kk = 0; kk < 4; ++kk)
      a[kk] = *(const s16x8*)(bufB + l16 * 136 + kk * 32 + quad * 8);
    f32x4 aF[2], aB[2]; aF[0] = zz4; aF[1] = zz4; aB[0] = zz4; aB[1] = zz4;
#pragma unroll
    for (int nt = 0; nt < 2; ++nt) {
      int n = wv * 32 + nt * 16 + l16;
#pragma unroll
      for (int kk = 0; kk < 4; ++kk) {
        aF[nt] = mfma16(a[kk], *(const s16x8*)(wfore + n * 128 + kk * 32 + quad * 8), aF[nt]);
        aB[nt] = mfma16(a[kk], *(const s16x8*)(wback + n * 128 + kk * 32 + quad * 8), aB[nt]);
      }
    }
#pragma unroll
    for (int nt = 0; nt < 2; ++nt) {
      int n = wv * 32 + nt * 16 + l16;
      float bf_ = b_fore[n], bb_ = b_back[n];
#pragma unroll
      for (int i = 0; i < 4; ++i) {
        int m = quad * 4 + i;
        bufF[m * 132 + n] = lrelu(aF[nt][i] + bf_);
        float back = lrelu(aB[nt][i] + bb_);
        float gv = g[(size_t)(r0 + m) * 128 + n];
        bufin[m * 136 + n] = f2bf(gv - back);
      }
    }
  }
  __syncthreads();
  {
    s16x8 a[4];
#pragma unroll
    for (int kk = 0; kk < 4; ++kk)
      a[kk] = *(const s16x8*)(bufin + l16 * 136 + kk * 32 + quad * 8);
    f32x4 acc[2]; acc[0] = zz4; acc[1] = zz4;
#pragma unroll
    for (int nt = 0; nt < 2; ++nt) {
      int n = wv * 32 + nt * 16 + l16;
#pragma unroll
      for (int kk = 0; kk < 4; ++kk)
        acc[nt] = mfma16(a[kk], *(const s16x8*)(windi + n * 128 + kk * 32 + quad * 8), acc[nt]);
    }
#pragma unroll
    for (int nt = 0; nt < 2; ++nt) {
      int n = wv * 32 + nt * 16 + l16;
      float bi_ = b_indi[n];
#pragma unroll
      for (int i = 0; i < 4; ++i)
        bufF[(quad * 4 + i) * 132 + n] += lrelu(acc[nt][i] + bi_);
    }
  }
  __syncthreads();
  if (tid < 16) {
    float s = b_out[0];
    const float* fr = bufF + tid * 132;
    for (int n = 0; n < 128; ++n) s += fr[n] * shWout[n];
    outp[r0 + tid] = s;
  }
}

// ---------------------------------------------------------------- workspace layout
static const size_t OFF_A       = 0;             // 67,108,864  sim fp32
static const size_t OFF_ATTN    = 67108864;      // 33,554,432  attn numerator bf16
static const size_t OFF_G       = 100663296;
static const size_t OFF_GBF     = 102760448;
static const size_t OFF_RNG     = 103809024;
static const size_t OFF_SELJ    = 103825408;
static const size_t OFF_SELV    = 104153088;
static const size_t OFF_EID     = 104480768;
static const size_t OFF_EV      = 104808448;
static const size_t OFF_CNT     = 105136128;
static const size_t OFF_TOUCH   = 105152512;
static const size_t OFF_COLSUM  = 105168896;
static const size_t OFF_OFFS    = 105185280;
static const size_t OFF_CUR     = 105201664;
static const size_t OFF_CF      = 105218048;
static const size_t OFF_CFBF    = 107315200;
static const size_t OFF_CFTS    = 108363776;
static const size_t OFF_RNCF    = 109412352;
static const size_t OFF_HSPRE   = 109428736;
static const size_t OFF_WB      = 111525888;

extern "C" void kernel_launch(void* const* d_in, const int* in_sizes, int n_in,
                              void* d_out, int out_size, void* d_ws, size_t ws_size,
                              hipStream_t stream)
{
  (void)in_sizes; (void)n_in; (void)out_size; (void)ws_size;
  const float* x      = (const float*)d_in[0];
  const float* Wih0   = (const float*)d_in[1];
  const float* Whh0   = (const float*)d_in[2];
  const float* bih0   = (const float*)d_in[3];
  const float* bhh0   = (const float*)d_in[4];
  const float* Wih1   = (const float*)d_in[5];
  const float* Whh1   = (const float*)d_in[6];
  const float* bih1   = (const float*)d_in[7];
  const float* bhh1   = (const float*)d_in[8];
  const float* W_hc   = (const float*)d_in[9];
  const float* b_hc   = (const float*)d_in[10];
  const float* W_hs   = (const float*)d_in[11];
  const float* b_hs   = (const float*)d_in[12];
  const float* W_fore = (const float*)d_in[13];
  const float* b_fore = (const float*)d_in[14];
  const float* W_back = (const float*)d_in[15];
  const float* b_back = (const float*)d_in[16];
  const float* W_indi = (const float*)d_in[17];
  const float* b_indi = (const float*)d_in[18];
  const float* W_out  = (const float*)d_in[19];
  const float* b_out  = (const float*)d_in[20];

  char* ws = (char*)d_ws;
  float* simbuf  = (float*)(ws + OFF_A);
  u16*   attnb   = (u16*)(ws + OFF_ATTN);
  float* gbuf    = (float*)(ws + OFF_G);
  u16*   gbf     = (u16*)(ws + OFF_GBF);
  float* rng     = (float*)(ws + OFF_RNG);
  int*   gselj   = (int*)(ws + OFF_SELJ);
  float* gselv   = (float*)(ws + OFF_SELV);
  int*   eid     = (int*)(ws + OFF_EID);
  float* ev      = (float*)(ws + OFF_EV);
  int*   cntb    = (int*)(ws + OFF_CNT);
  int*   touched = (int*)(ws + OFF_TOUCH);
  float* colsum  = (float*)(ws + OFF_COLSUM);
  int*   offsb   = (int*)(ws + OFF_OFFS);
  int*   curb    = (int*)(ws + OFF_CUR);
  float* cf      = (float*)(ws + OFF_CF);
  u16*   cfbf    = (u16*)(ws + OFF_CFBF);
  u16*   cfTs    = (u16*)(ws + OFF_CFTS);
  float* rncf    = (float*)(ws + OFF_RNCF);
  float* hs_pre  = (float*)(ws + OFF_HSPRE);
  u16*   wsB     = (u16*)(ws + OFF_WB);
  u16 *wih0b = wsB, *whh0b = wsB + 12288, *wih1b = wsB + 61440, *whh1b = wsB + 110592;
  u16 *whsb = wsB + 159744, *wforeb = wsB + 176128, *wbackb = wsB + 192512, *windib = wsB + 208896;

  cvt_all<<<880, 256, 0, stream>>>(Wih0, Whh0, Wih1, Whh1, W_hs, W_fore, W_back, W_indi, wsB);

  gru_fused<<<256, 512, 0, stream>>>(x, wih0b, whh0b, bih0, bhh0,
                                     wih1b, whh1b, bih1, bhh1, gbuf);

  norm_cvt<<<1024, 256, 0, stream>>>(gbuf, gbf, rng);
  cos_gemm<0><<<dim3(32, 32), 256, 0, stream>>>(gbf, gbf, rng, rng, simbuf,
                                                (u16*)nullptr, (float*)nullptr);

  hipMemsetAsync(ws + OFF_CNT, 0, 49152, stream);
  topk_select<<<4096, 256, 0, stream>>>(simbuf, gselj, gselv, cntb, touched);
  scan4096<<<1, 1024, 0, stream>>>(cntb, offsb, curb);
  scatter_entries<<<320, 256, 0, stream>>>(gselj, gselv, curb, eid, ev);
  concept_cf<<<4096, 128, 0, stream>>>(offsb, cntb, eid, ev, gbuf, simbuf, touched,
                                       W_hc, b_hc, cf, cfbf, rncf);

  cos_gemm<1><<<dim3(32, 32), 256, 0, stream>>>(gbf, cfbf, rng, rncf, (float*)nullptr,
                                                attnb, colsum);
  scale_cfT<<<2048, 256, 0, stream>>>(cf, colsum, cfTs);
  attn_cf<<<256, 256, 0, stream>>>(attnb, cfTs, hs_pre);

  head_kernel<<<256, 256, 0, stream>>>(hs_pre, gbuf, whsb, wforeb, wbackb, windib,
                                       b_hs, b_fore, b_back, b_indi, W_out, b_out,
                                       (float*)d_out);
}